// Round 3
// baseline (1687.124 us; speedup 1.0000x reference)
//
#include <hip/hip_runtime.h>
#include <hip/hip_bf16.h>
#include <cstdint>
#include <cstddef>

// Problem constants
static constexpr int Bc = 2, Tc = 2048, Dc = 1024, Hc = 16, HKVc = 4, HDc = 64;
static constexpr int Mc = Bc * Tc;                 // 4096 rows
static constexpr float EPSc = 1.1920929e-07f;

// ---------------- numpy-exact fp32 pairwise abs-mean ----------------
// numpy pairwise_sum: leaves of 128 elements with 8 accumulators
// r[j] = |a[j]| + |a[8+j]| + ... + |a[120+j]|  (sequential, 15 adds)
// leaf = ((r0+r1)+(r2+r3)) + ((r4+r5)+(r6+r7))
// then power-of-two in-order binary tree over leaves.
__global__ __launch_bounds__(256) void np_leafsum(const float* __restrict__ w,
                                                  float* __restrict__ leaf, int nleaves) {
  int t = blockIdx.x * 256 + threadIdx.x;
  int lf = t >> 3, j = t & 7;
  if (lf >= nleaves) return;
  const float* a = w + (size_t)lf * 128;
  float r = fabsf(a[j]);
#pragma unroll
  for (int i = 8; i < 128; i += 8) r += fabsf(a[i + j]);
  float x = r + __shfl_xor(r, 1);   // (r0+r1) on even lanes (fp add commutative -> exact)
  float y = x + __shfl_xor(x, 2);   // (r0+r1)+(r2+r3)
  float z = y + __shfl_xor(y, 4);   // ((r0+r1)+(r2+r3))+((r4+r5)+(r6+r7))
  if (j == 0) leaf[lf] = z;
}

__global__ __launch_bounds__(1024) void np_treemean(const float* __restrict__ leaf,
                                                    int nleaves, float inv_n,
                                                    float* __restrict__ th) {
  __shared__ float s[8192];
  int tid = threadIdx.x;
  for (int i = tid; i < nleaves; i += 1024) s[i] = leaf[i];
  __syncthreads();
  for (int cnt = nleaves >> 1; cnt >= 1; cnt >>= 1) {
    float v[4];
    int nv = 0;
    for (int i = tid; i < cnt; i += 1024) { v[nv] = s[2 * i] + s[2 * i + 1]; ++nv; }
    __syncthreads();
    nv = 0;
    for (int i = tid; i < cnt; i += 1024) { s[i] = v[nv]; ++nv; }
    __syncthreads();
  }
  if (tid == 0) th[0] = s[0] * inv_n;   // n is a power of two -> exact scaling, matches np
}

// ---------------- ternary quantize: {-1,0,+1} in fp32, fp32 threshold (numpy-exact) ----------------
__global__ __launch_bounds__(256) void ternary_quant(const float* __restrict__ w,
                                                     const float* __restrict__ thp,
                                                     float* __restrict__ o, int n) {
  float th = thp[0];
  int i = blockIdx.x * 256 + threadIdx.x;
  if (i < n) {
    float x = w[i];
    o[i] = (x > th) ? 1.0f : ((x < -th) ? -1.0f : 0.0f);
  }
}

// ---------------- per-row 1/sqrt(mean(x^2)+eps) in fp64 ----------------
__global__ __launch_bounds__(256) void row_inv_rms(const float* __restrict__ X,
                                                   double* __restrict__ invx) {
  int row = blockIdx.x;
  const float* xr = X + (size_t)row * Dc;
  int tid = threadIdx.x;
  float4 v = *(const float4*)&xr[tid * 4];
  double ss = (double)v.x * (double)v.x + (double)v.y * (double)v.y +
              (double)v.z * (double)v.z + (double)v.w * (double)v.w;
#pragma unroll
  for (int off = 1; off < 64; off <<= 1) ss += __shfl_xor(ss, off);
  __shared__ double red[4];
  if ((tid & 63) == 0) red[tid >> 6] = ss;
  __syncthreads();
  if (tid == 0) {
    double tot = red[0] + red[1] + red[2] + red[3];
    invx[row] = 1.0 / sqrt(tot * (1.0 / 1024.0) + (double)EPSc);
  }
}

// ---------------- fp32 RMSNorm (output path, no tie sensitivity) ----------------
__global__ __launch_bounds__(256) void rmsnorm_f32(const float* __restrict__ X,
                                                   const float* __restrict__ g1,
                                                   float* __restrict__ O1) {
  int row = blockIdx.x;
  const float* xr = X + (size_t)row * Dc;
  int tid = threadIdx.x;
  float4 v = *(const float4*)&xr[tid * 4];
  float ss = v.x * v.x + v.y * v.y + v.z * v.z + v.w * v.w;
#pragma unroll
  for (int off = 1; off < 64; off <<= 1) ss += __shfl_xor(ss, off);
  __shared__ float red[4];
  if ((tid & 63) == 0) red[tid >> 6] = ss;
  __syncthreads();
  float tot = red[0] + red[1] + red[2] + red[3];
  float inv = 1.0f / sqrtf(tot * (1.0f / (float)Dc) + EPSc);
  float4 a = *(const float4*)&g1[tid * 4];
  float4 o1 = make_float4(v.x * inv * a.x, v.y * inv * a.y, v.z * inv * a.z, v.w * inv * a.w);
  *(float4*)&O1[(size_t)row * Dc + tid * 4] = o1;
}

// ---------------- fp64-accum ternary GEMM: C64[M,N] = (x*g)[M,K] @ Wt[N,K]^T ----------------
__global__ __launch_bounds__(256) void gemm_nt_tern64(const float* __restrict__ X,
                                                      const float* __restrict__ g,
                                                      const float* __restrict__ Wt,
                                                      double* __restrict__ C,
                                                      int N, int K) {
  __shared__ double As[16][68];   // [k][m]
  __shared__ double Bs[16][68];   // [k][n]
  int tid = threadIdx.x;
  int tm = tid & 15, tn = tid >> 4;
  int bm = blockIdx.y * 64, bn = blockIdx.x * 64;
  int lk = tid & 15, lm = tid >> 4;
  double acc[4][4] = {};
  for (int kb = 0; kb < K; kb += 16) {
#pragma unroll
    for (int s4 = 0; s4 < 4; ++s4) {
      int m = lm + s4 * 16;
      As[lk][m] = (double)X[(size_t)(bm + m) * K + kb + lk] * (double)g[kb + lk];
      Bs[lk][m] = (double)Wt[(size_t)(bn + m) * K + kb + lk];
    }
    __syncthreads();
#pragma unroll
    for (int k = 0; k < 16; ++k) {
      double a0 = As[k][tm * 4 + 0], a1 = As[k][tm * 4 + 1];
      double a2 = As[k][tm * 4 + 2], a3 = As[k][tm * 4 + 3];
      double b0 = Bs[k][tn * 4 + 0], b1 = Bs[k][tn * 4 + 1];
      double b2 = Bs[k][tn * 4 + 2], b3 = Bs[k][tn * 4 + 3];
      acc[0][0] += a0 * b0; acc[0][1] += a0 * b1; acc[0][2] += a0 * b2; acc[0][3] += a0 * b3;
      acc[1][0] += a1 * b0; acc[1][1] += a1 * b1; acc[1][2] += a1 * b2; acc[1][3] += a1 * b3;
      acc[2][0] += a2 * b0; acc[2][1] += a2 * b1; acc[2][2] += a2 * b2; acc[2][3] += a2 * b3;
      acc[3][0] += a3 * b0; acc[3][1] += a3 * b1; acc[3][2] += a3 * b2; acc[3][3] += a3 * b3;
    }
    __syncthreads();
  }
#pragma unroll
  for (int i = 0; i < 4; ++i)
#pragma unroll
    for (int j = 0; j < 4; ++j)
      C[(size_t)(bm + tm * 4 + i) * N + bn + tn * 4 + j] = acc[i][j];
}

// ---------------- fp32 GEMM:  C[M,N] = A[M,K] @ B[N,K]^T ----------------
__global__ __launch_bounds__(256) void gemm_nt_f32(const float* __restrict__ A,
                                                   const float* __restrict__ B,
                                                   float* __restrict__ C,
                                                   int M, int N, int K) {
  __shared__ float As[16][68];
  __shared__ float Bs[16][68];
  int tid = threadIdx.x;
  int tm = tid & 15, tn = tid >> 4;
  int bm = blockIdx.y * 64, bn = blockIdx.x * 64;
  int lk = tid & 15, lm = tid >> 4;
  float acc[4][4] = {};
  for (int kb = 0; kb < K; kb += 16) {
#pragma unroll
    for (int s4 = 0; s4 < 4; ++s4) {
      int m = lm + s4 * 16;
      As[lk][m] = A[(size_t)(bm + m) * K + kb + lk];
      Bs[lk][m] = B[(size_t)(bn + m) * K + kb + lk];
    }
    __syncthreads();
#pragma unroll
    for (int k = 0; k < 16; ++k) {
      float4 a = *(const float4*)&As[k][tm * 4];
      float4 b = *(const float4*)&Bs[k][tn * 4];
      acc[0][0] += a.x * b.x; acc[0][1] += a.x * b.y; acc[0][2] += a.x * b.z; acc[0][3] += a.x * b.w;
      acc[1][0] += a.y * b.x; acc[1][1] += a.y * b.y; acc[1][2] += a.y * b.z; acc[1][3] += a.y * b.w;
      acc[2][0] += a.z * b.x; acc[2][1] += a.z * b.y; acc[2][2] += a.z * b.z; acc[2][3] += a.z * b.w;
      acc[3][0] += a.w * b.x; acc[3][1] += a.w * b.y; acc[3][2] += a.w * b.z; acc[3][3] += a.w * b.w;
    }
    __syncthreads();
  }
#pragma unroll
  for (int i = 0; i < 4; ++i) {
    float4 o = make_float4(acc[i][0], acc[i][1], acc[i][2], acc[i][3]);
    *(float4*)&C[(size_t)(bm + tm * 4 + i) * N + bn + tn * 4] = o;
  }
}

// ---------------- flash-style causal GQA attention, fp64 logits ----------------
__global__ __launch_bounds__(256) void attn_kernel64(const double* __restrict__ Q,
                                                     const double* __restrict__ Kg,
                                                     const float* __restrict__ Vg,
                                                     const double* __restrict__ invx,
                                                     float* __restrict__ Og,
                                                     const float* __restrict__ qk_gain) {
  constexpr int TQ = 32, TK = 64;
  __shared__ double Qs[TQ][66];
  __shared__ double Ks[TK][66];
  __shared__ float Vs[TK][68];
  __shared__ float Ps[TQ][68];
  __shared__ double iK[TK];
  int tid = threadIdx.x;
  int q0 = blockIdx.x * TQ;
  int h = blockIdx.y;
  int b = blockIdx.z;
  int kvh = h >> 2;
  const double scale = (double)qk_gain[0] * 0.125;
  int r = tid >> 3, c = tid & 7;
  for (int i = tid; i < TQ * 64; i += 256) {
    int rr = i >> 6, d = i & 63;
    Qs[rr][d] = Q[((size_t)(b * Tc + q0 + rr)) * Dc + h * 64 + d];
  }
  double invq = invx[b * Tc + q0 + r];
  double m = -1e300;
  float l = 0.0f;
  float O[8] = {0, 0, 0, 0, 0, 0, 0, 0};
  int qi = q0 + r;
  for (int k0 = 0; k0 < q0 + TQ; k0 += TK) {
    __syncthreads();  // prev PV done; Q tile visible on iter 0
    for (int i = tid; i < TK * 64; i += 256) {
      int j = i >> 6, d = i & 63;
      size_t gk = ((size_t)(b * Tc + k0 + j)) * (HKVc * HDc) + kvh * 64 + d;
      Ks[j][d] = Kg[gk];
      Vs[j][d] = Vg[gk];
    }
    if (tid < TK) iK[tid] = invx[b * Tc + k0 + tid] * scale;
    __syncthreads();
    double s[8] = {0, 0, 0, 0, 0, 0, 0, 0};
    for (int d = 0; d < 64; ++d) {
      double qd = Qs[r][d];
#pragma unroll
      for (int jj = 0; jj < 8; ++jj) s[jj] += qd * Ks[c + 8 * jj][d];
    }
    double tmax = -1e300;
#pragma unroll
    for (int jj = 0; jj < 8; ++jj) {
      int kj = k0 + c + 8 * jj;
      double val = s[jj] * (invq * iK[c + 8 * jj]);
      s[jj] = (kj <= qi) ? val : -1e300;
      tmax = fmax(tmax, s[jj]);
    }
#pragma unroll
    for (int off = 1; off < 8; off <<= 1) tmax = fmax(tmax, __shfl_xor(tmax, off));
    double mn = fmax(m, tmax);
    float corr = __expf((float)(m - mn));
    float rsum = 0.0f;
#pragma unroll
    for (int jj = 0; jj < 8; ++jj) {
      float p = __expf((float)(s[jj] - mn));
      Ps[r][c + 8 * jj] = p;
      rsum += p;
    }
#pragma unroll
    for (int off = 1; off < 8; off <<= 1) rsum += __shfl_xor(rsum, off);
    m = mn;
    l = l * corr + rsum;
#pragma unroll
    for (int dd = 0; dd < 8; ++dd) O[dd] *= corr;
    __syncthreads();  // Ps visible
    for (int j = 0; j < TK; ++j) {
      float p = Ps[r][j];
      float4 vA = *(const float4*)&Vs[j][c * 8];
      float4 vB = *(const float4*)&Vs[j][c * 8 + 4];
      O[0] += p * vA.x; O[1] += p * vA.y; O[2] += p * vA.z; O[3] += p * vA.w;
      O[4] += p * vB.x; O[5] += p * vB.y; O[6] += p * vB.z; O[7] += p * vB.w;
    }
  }
  float inv = 1.0f / l;
  size_t base = ((size_t)(b * Tc + q0 + r)) * Dc + h * 64 + c * 8;
  float4 o1 = make_float4(O[0] * inv, O[1] * inv, O[2] * inv, O[3] * inv);
  float4 o2 = make_float4(O[4] * inv, O[5] * inv, O[6] * inv, O[7] * inv);
  *(float4*)&Og[base] = o1;
  *(float4*)&Og[base + 4] = o2;
}

// ---------------- launch ----------------
extern "C" void kernel_launch(void* const* d_in, const int* in_sizes, int n_in,
                              void* d_out, int out_size, void* d_ws, size_t ws_size,
                              hipStream_t stream) {
  const float* x    = (const float*)d_in[0];
  const float* q_w  = (const float*)d_in[1];
  const float* q_g  = (const float*)d_in[2];
  const float* k_w  = (const float*)d_in[3];
  const float* k_g  = (const float*)d_in[4];
  const float* v_w  = (const float*)d_in[5];
  const float* o_w  = (const float*)d_in[6];
  const float* o_g  = (const float*)d_in[7];
  const float* qk_g = (const float*)d_in[8];

  // workspace layout; peak ~60.1 MiB
  float* ws = (float*)d_ws;
  float* AO  = ws;                        // 4M floats (attention out). Early: Wq+Wk. Late: Wo.
  float* Wq  = ws;                        // 1M floats   [dead before attention writes AO]
  float* Wk  = ws + 1048576;              // 256K floats [dead before attention writes AO]
  float* Wo  = ws;                        // 1M floats, quantized AFTER AO is consumed
  float* Vm  = ws + 4194304;              // 1M floats
  double* Aq = (double*)(Vm + 1048576);   // 4M doubles
  double* Ak = Aq + 4194304;              // 1M doubles
  double* invx = Ak + 1048576;            // 4096 doubles
  float* leaf  = (float*)(invx + 4096);   // 8192 floats (reused per matrix, stream-ordered)
  float* th    = leaf + 8192;             // 3 floats
  float* Xo  = (float*)Aq;                // 4M floats overlay (Aq dead after attention)

  // 1) numpy-exact fp32 thresholds: th = float32 pairwise mean(|w|)
  np_leafsum<<<256, 256, 0, stream>>>(q_w, leaf, 8192);
  np_treemean<<<1, 1024, 0, stream>>>(leaf, 8192, 1.0f / 1048576.0f, th + 0);
  np_leafsum<<<64, 256, 0, stream>>>(k_w, leaf, 2048);
  np_treemean<<<1, 1024, 0, stream>>>(leaf, 2048, 1.0f / 262144.0f, th + 1);
  np_leafsum<<<256, 256, 0, stream>>>(o_w, leaf, 8192);
  np_treemean<<<1, 1024, 0, stream>>>(leaf, 8192, 1.0f / 1048576.0f, th + 2);

  // 2) quantize q/k ternary weights (fp32 compare, numpy-exact decisions)
  ternary_quant<<<4096, 256, 0, stream>>>(q_w, th + 0, Wq, 1048576);
  ternary_quant<<<1024, 256, 0, stream>>>(k_w, th + 1, Wk, 262144);

  // 3) per-row inverse RMS of x (fp64)
  row_inv_rms<<<Mc, 256, 0, stream>>>(x, invx);

  // 4) projections: Q,K fp64 ternary (norm folded into logits); V fp32
  gemm_nt_tern64<<<dim3(16, 64), 256, 0, stream>>>(x, q_g, Wq, Aq, 1024, 1024);
  gemm_nt_tern64<<<dim3(4, 64), 256, 0, stream>>>(x, k_g, Wk, Ak, 256, 1024);
  gemm_nt_f32<<<dim3(4, 64), 256, 0, stream>>>(x, v_w, Vm, Mc, 256, 1024);

  // 5) causal GQA attention with fp64 logits -> AO fp32 [4096,1024]
  attn_kernel64<<<dim3(Tc / 32, Hc, Bc), 256, 0, stream>>>(Aq, Ak, Vm, invx, AO, qk_g);

  // 6) output bitlinear: RMSNorm(AO)*o_g -> Xo; quantize o_w (AO now dead); GEMM -> d_out
  rmsnorm_f32<<<Mc, 256, 0, stream>>>(AO, o_g, Xo);
  ternary_quant<<<4096, 256, 0, stream>>>(o_w, th + 2, Wo, 1048576);
  gemm_nt_f32<<<dim3(16, 64), 256, 0, stream>>>(Xo, Wo, (float*)d_out, Mc, 1024, 1024);
}

// Round 4
// 1095.180 us; speedup vs baseline: 1.5405x; 1.5405x over previous
//
#include <hip/hip_runtime.h>
#include <hip/hip_bf16.h>
#include <cstdint>
#include <cstddef>

// Problem constants
static constexpr int Bc = 2, Tc = 2048, Dc = 1024, Hc = 16, HKVc = 4, HDc = 64;
static constexpr int Mc = Bc * Tc;                 // 4096 rows
static constexpr float EPSc = 1.1920929e-07f;

// ---------------- numpy-exact fp32 pairwise abs-mean (verified round 3) ----------------
__global__ __launch_bounds__(256) void np_leafsum(const float* __restrict__ w,
                                                  float* __restrict__ leaf, int nleaves) {
  int t = blockIdx.x * 256 + threadIdx.x;
  int lf = t >> 3, j = t & 7;
  if (lf >= nleaves) return;
  const float* a = w + (size_t)lf * 128;
  float r = fabsf(a[j]);
#pragma unroll
  for (int i = 8; i < 128; i += 8) r += fabsf(a[i + j]);
  float x = r + __shfl_xor(r, 1);
  float y = x + __shfl_xor(x, 2);
  float z = y + __shfl_xor(y, 4);
  if (j == 0) leaf[lf] = z;
}

__global__ __launch_bounds__(1024) void np_treemean(const float* __restrict__ leaf,
                                                    int nleaves, float inv_n,
                                                    float* __restrict__ th) {
  __shared__ float s[8192];
  int tid = threadIdx.x;
  for (int i = tid; i < nleaves; i += 1024) s[i] = leaf[i];
  __syncthreads();
  for (int cnt = nleaves >> 1; cnt >= 1; cnt >>= 1) {
    float v[4];
    int nv = 0;
    for (int i = tid; i < cnt; i += 1024) { v[nv] = s[2 * i] + s[2 * i + 1]; ++nv; }
    __syncthreads();
    nv = 0;
    for (int i = tid; i < cnt; i += 1024) { s[i] = v[nv]; ++nv; }
    __syncthreads();
  }
  if (tid == 0) th[0] = s[0] * inv_n;
}

// ---------------- ternary quantize (fp32 compare vs numpy-exact th) ----------------
__global__ __launch_bounds__(256) void ternary_quant(const float* __restrict__ w,
                                                     const float* __restrict__ thp,
                                                     float* __restrict__ o, int n) {
  float th = thp[0];
  int i = blockIdx.x * 256 + threadIdx.x;
  if (i < n) {
    float x = w[i];
    o[i] = (x > th) ? 1.0f : ((x < -th) ? -1.0f : 0.0f);
  }
}

// ---------------- RMSNorm, one row/block, optional second gain ----------------
__global__ __launch_bounds__(256) void rmsnorm2(const float* __restrict__ X,
                                                const float* __restrict__ g1,
                                                const float* __restrict__ g2,
                                                float* __restrict__ O1,
                                                float* __restrict__ O2) {
  int row = blockIdx.x;
  const float* xr = X + (size_t)row * Dc;
  int tid = threadIdx.x;
  float4 v = *(const float4*)&xr[tid * 4];
  float ss = v.x * v.x + v.y * v.y + v.z * v.z + v.w * v.w;
#pragma unroll
  for (int off = 1; off < 64; off <<= 1) ss += __shfl_xor(ss, off);
  __shared__ float red[4];
  if ((tid & 63) == 0) red[tid >> 6] = ss;
  __syncthreads();
  float tot = red[0] + red[1] + red[2] + red[3];
  float inv = 1.0f / sqrtf(tot * (1.0f / (float)Dc) + EPSc);
  float4 a = *(const float4*)&g1[tid * 4];
  *(float4*)&O1[(size_t)row * Dc + tid * 4] =
      make_float4(v.x * inv * a.x, v.y * inv * a.y, v.z * inv * a.z, v.w * inv * a.w);
  if (O2 != nullptr) {
    float4 b2 = *(const float4*)&g2[tid * 4];
    *(float4*)&O2[(size_t)row * Dc + tid * 4] =
        make_float4(v.x * inv * b2.x, v.y * inv * b2.y, v.z * inv * b2.z, v.w * inv * b2.w);
  }
}

// ---------------- fp32 GEMM, 128x64 tile, 8x4 acc:  C[M,N] = A[M,K] @ B[N,K]^T ----------------
// block 256 thr; per-thread m-frags at tm*4 and 64+tm*4 (2-way LDS alias = free), n-frag tn*4.
__global__ __launch_bounds__(256) void gemm_nt_f32_v2(const float* __restrict__ A,
                                                      const float* __restrict__ B,
                                                      float* __restrict__ C,
                                                      int M, int N, int K) {
  __shared__ float As[16][132];   // [k][m], pad +4
  __shared__ float Bs[16][68];    // [k][n]
  int tid = threadIdx.x;
  int bm = blockIdx.y * 128, bn = blockIdx.x * 64;
  int lr = tid >> 2;              // 0..63
  int lk = (tid & 3) * 4;         // 0,4,8,12
  int tm = tid & 15, tn = tid >> 4;
  float acc[8][4] = {};
  for (int kb = 0; kb < K; kb += 16) {
    float4 a0 = *(const float4*)&A[(size_t)(bm + lr) * K + kb + lk];
    float4 a1 = *(const float4*)&A[(size_t)(bm + 64 + lr) * K + kb + lk];
    float4 b0 = *(const float4*)&B[(size_t)(bn + lr) * K + kb + lk];
    As[lk + 0][lr] = a0.x; As[lk + 1][lr] = a0.y; As[lk + 2][lr] = a0.z; As[lk + 3][lr] = a0.w;
    As[lk + 0][64 + lr] = a1.x; As[lk + 1][64 + lr] = a1.y; As[lk + 2][64 + lr] = a1.z; As[lk + 3][64 + lr] = a1.w;
    Bs[lk + 0][lr] = b0.x; Bs[lk + 1][lr] = b0.y; Bs[lk + 2][lr] = b0.z; Bs[lk + 3][lr] = b0.w;
    __syncthreads();
#pragma unroll
    for (int k = 0; k < 16; ++k) {
      float4 aA = *(const float4*)&As[k][tm * 4];
      float4 aB = *(const float4*)&As[k][64 + tm * 4];
      float4 bb = *(const float4*)&Bs[k][tn * 4];
      float av[8] = {aA.x, aA.y, aA.z, aA.w, aB.x, aB.y, aB.z, aB.w};
#pragma unroll
      for (int i = 0; i < 8; ++i) {
        acc[i][0] += av[i] * bb.x;
        acc[i][1] += av[i] * bb.y;
        acc[i][2] += av[i] * bb.z;
        acc[i][3] += av[i] * bb.w;
      }
    }
    __syncthreads();
  }
#pragma unroll
  for (int i = 0; i < 8; ++i) {
    int row = bm + ((i < 4) ? (tm * 4 + i) : (64 + tm * 4 + (i - 4)));
    *(float4*)&C[(size_t)row * N + bn + tn * 4] =
        make_float4(acc[i][0], acc[i][1], acc[i][2], acc[i][3]);
  }
}

// ---------------- flash-style causal GQA attention (fp32, scale folded into Q) ----------------
// Grid: (T/32, H, B). Block 256 = 32 q-rows x 8 lanes.
__global__ __launch_bounds__(256) void attn_kernel(const float* __restrict__ Q,
                                                   const float* __restrict__ Kg,
                                                   const float* __restrict__ Vg,
                                                   float* __restrict__ Og,
                                                   const float* __restrict__ qk_gain) {
  constexpr int TQ = 32, TK = 64;
  __shared__ float Qs[TQ][68];
  __shared__ float Ks[TK][68];
  __shared__ float Vs[TK][68];
  __shared__ float Ps[TQ][68];
  int tid = threadIdx.x;
  int q0 = blockIdx.x * TQ;
  int h = blockIdx.y;
  int b = blockIdx.z;
  int kvh = h >> 2;
  const float scale = qk_gain[0] * 0.125f;
  int r = tid >> 3, c = tid & 7;
  for (int i = tid; i < TQ * 64; i += 256) {
    int rr = i >> 6, d = i & 63;
    Qs[rr][d] = Q[((size_t)(b * Tc + q0 + rr)) * Dc + h * 64 + d] * scale;
  }
  float m = -1e30f, l = 0.0f;
  float O[8] = {0, 0, 0, 0, 0, 0, 0, 0};
  int qi = q0 + r;
  for (int k0 = 0; k0 < q0 + TQ; k0 += TK) {
    __syncthreads();  // prev PV done; Q tile visible on iter 0
    for (int i = tid; i < TK * 64; i += 256) {
      int j = i >> 6, d = i & 63;
      size_t gk = ((size_t)(b * Tc + k0 + j)) * (HKVc * HDc) + kvh * 64 + d;
      Ks[j][d] = Kg[gk];
      Vs[j][d] = Vg[gk];
    }
    __syncthreads();
    float s[8] = {0, 0, 0, 0, 0, 0, 0, 0};
    for (int d4 = 0; d4 < 16; ++d4) {
      float4 q4 = *(const float4*)&Qs[r][d4 * 4];
#pragma unroll
      for (int jj = 0; jj < 8; ++jj) {
        float4 k4 = *(const float4*)&Ks[c + 8 * jj][d4 * 4];
        s[jj] += q4.x * k4.x + q4.y * k4.y + q4.z * k4.z + q4.w * k4.w;
      }
    }
    float tmax = -1e30f;
#pragma unroll
    for (int jj = 0; jj < 8; ++jj) {
      int kj = k0 + c + 8 * jj;
      s[jj] = (kj <= qi) ? s[jj] : -1e30f;
      tmax = fmaxf(tmax, s[jj]);
    }
#pragma unroll
    for (int off = 1; off < 8; off <<= 1) tmax = fmaxf(tmax, __shfl_xor(tmax, off));
    float mn = fmaxf(m, tmax);
    float corr = __expf(m - mn);
    float rsum = 0.0f;
#pragma unroll
    for (int jj = 0; jj < 8; ++jj) {
      float p = __expf(s[jj] - mn);
      Ps[r][c + 8 * jj] = p;
      rsum += p;
    }
#pragma unroll
    for (int off = 1; off < 8; off <<= 1) rsum += __shfl_xor(rsum, off);
    m = mn;
    l = l * corr + rsum;
#pragma unroll
    for (int dd = 0; dd < 8; ++dd) O[dd] *= corr;
    __syncthreads();  // Ps visible
    for (int j = 0; j < TK; ++j) {
      float p = Ps[r][j];
      float4 vA = *(const float4*)&Vs[j][c * 8];
      float4 vB = *(const float4*)&Vs[j][c * 8 + 4];
      O[0] += p * vA.x; O[1] += p * vA.y; O[2] += p * vA.z; O[3] += p * vA.w;
      O[4] += p * vB.x; O[5] += p * vB.y; O[6] += p * vB.z; O[7] += p * vB.w;
    }
  }
  float inv = 1.0f / l;
  size_t base = ((size_t)(b * Tc + q0 + r)) * Dc + h * 64 + c * 8;
  *(float4*)&Og[base] = make_float4(O[0] * inv, O[1] * inv, O[2] * inv, O[3] * inv);
  *(float4*)&Og[base + 4] = make_float4(O[4] * inv, O[5] * inv, O[6] * inv, O[7] * inv);
}

// ---------------- launch ----------------
extern "C" void kernel_launch(void* const* d_in, const int* in_sizes, int n_in,
                              void* d_out, int out_size, void* d_ws, size_t ws_size,
                              hipStream_t stream) {
  const float* x    = (const float*)d_in[0];
  const float* q_w  = (const float*)d_in[1];
  const float* q_g  = (const float*)d_in[2];
  const float* k_w  = (const float*)d_in[3];
  const float* k_g  = (const float*)d_in[4];
  const float* v_w  = (const float*)d_in[5];
  const float* o_w  = (const float*)d_in[6];
  const float* o_g  = (const float*)d_in[7];
  const float* qk_g = (const float*)d_in[8];

  // workspace layout (floats); ~65.1 MB
  float* ws = (float*)d_ws;
  float* Wq = ws;                        // 1M
  float* Wk = Wq + 1048576;              // 256K
  float* Wo = Wk + 262144;               // 1M
  float* Xq = Wo + 1048576;              // 4M   (AO overlays after Q gemm)
  float* Xk = Xq + 4194304;              // 4M   (Xo overlays after K gemm)
  float* Qm = Xk + 4194304;              // 4M
  float* Km = Qm + 4194304;              // 1M
  float* Vm = Km + 1048576;              // 1M
  float* leaf = Vm + 1048576;            // 8192
  float* th = leaf + 8192;               // 3
  float* AO = Xq;                        // overlay: Xq dead after Q gemm
  float* Xo = Xk;                        // overlay: Xk dead after K gemm

  // 1) numpy-exact fp32 thresholds
  np_leafsum<<<256, 256, 0, stream>>>(q_w, leaf, 8192);
  np_treemean<<<1, 1024, 0, stream>>>(leaf, 8192, 1.0f / 1048576.0f, th + 0);
  np_leafsum<<<64, 256, 0, stream>>>(k_w, leaf, 2048);
  np_treemean<<<1, 1024, 0, stream>>>(leaf, 2048, 1.0f / 262144.0f, th + 1);
  np_leafsum<<<256, 256, 0, stream>>>(o_w, leaf, 8192);
  np_treemean<<<1, 1024, 0, stream>>>(leaf, 8192, 1.0f / 1048576.0f, th + 2);

  // 2) quantize ternary weights
  ternary_quant<<<4096, 256, 0, stream>>>(q_w, th + 0, Wq, 1048576);
  ternary_quant<<<1024, 256, 0, stream>>>(k_w, th + 1, Wk, 262144);
  ternary_quant<<<4096, 256, 0, stream>>>(o_w, th + 2, Wo, 1048576);

  // 3) RMSNorm(x) with q_g and k_g gains
  rmsnorm2<<<Mc, 256, 0, stream>>>(x, q_g, k_g, Xq, Xk);

  // 4) projections (fp32): Q [4096,1024], K [4096,256], V [4096,256]
  gemm_nt_f32_v2<<<dim3(16, 32), 256, 0, stream>>>(Xq, Wq, Qm, Mc, 1024, 1024);
  gemm_nt_f32_v2<<<dim3(4, 32), 256, 0, stream>>>(Xk, Wk, Km, Mc, 256, 1024);
  gemm_nt_f32_v2<<<dim3(4, 32), 256, 0, stream>>>(x, v_w, Vm, Mc, 256, 1024);

  // 5) causal GQA attention -> AO [4096,1024]
  attn_kernel<<<dim3(Tc / 32, Hc, Bc), 256, 0, stream>>>(Qm, Km, Vm, AO, qk_g);

  // 6) output bitlinear: RMSNorm(AO)*o_g @ Wo^T -> d_out
  rmsnorm2<<<Mc, 256, 0, stream>>>(AO, o_g, o_g, Xo, nullptr);
  gemm_nt_f32_v2<<<dim3(16, 32), 256, 0, stream>>>(Xo, Wo, (float*)d_out, Mc, 1024, 1024);
}

// Round 5
// 605.208 us; speedup vs baseline: 2.7877x; 1.8096x over previous
//
#include <hip/hip_runtime.h>
#include <hip/hip_bf16.h>
#include <cstdint>
#include <cstddef>

typedef unsigned short u16;
typedef unsigned int u32;
typedef __attribute__((ext_vector_type(8))) short short8v;   // 8 bf16 (4 VGPRs) MFMA frag
typedef __attribute__((ext_vector_type(4))) float f32x4;     // MFMA accumulator
typedef __attribute__((ext_vector_type(4))) u16 u16x4;
typedef __attribute__((ext_vector_type(8))) u16 u16x8;

// Problem constants
static constexpr int Bc = 2, Tc = 2048, Dc = 1024, Hc = 16, HKVc = 4, HDc = 64;
static constexpr int Mc = Bc * Tc;                 // 4096 rows
static constexpr float EPSc = 1.1920929e-07f;

// RNE float->bf16 bits (finite inputs only)
static __device__ __forceinline__ u16 f2bf(float f) {
  u32 u = __builtin_bit_cast(u32, f);
  return (u16)((u + 0x7fffu + ((u >> 16) & 1u)) >> 16);
}
static __device__ __forceinline__ float bf2f(u16 b) {
  u32 u = ((u32)b) << 16;
  return __builtin_bit_cast(float, u);
}

// ---------------- numpy-exact fp32 pairwise abs-mean (verified round 3) ----------------
__global__ __launch_bounds__(256) void np_leafsum(const float* __restrict__ w,
                                                  float* __restrict__ leaf, int nleaves) {
  int t = blockIdx.x * 256 + threadIdx.x;
  int lf = t >> 3, j = t & 7;
  if (lf >= nleaves) return;
  const float* a = w + (size_t)lf * 128;
  float r = fabsf(a[j]);
#pragma unroll
  for (int i = 8; i < 128; i += 8) r += fabsf(a[i + j]);
  float x = r + __shfl_xor(r, 1);
  float y = x + __shfl_xor(x, 2);
  float z = y + __shfl_xor(y, 4);
  if (j == 0) leaf[lf] = z;
}

__global__ __launch_bounds__(1024) void np_treemean(const float* __restrict__ leaf,
                                                    int nleaves, float inv_n,
                                                    float* __restrict__ th) {
  __shared__ float s[8192];
  int tid = threadIdx.x;
  for (int i = tid; i < nleaves; i += 1024) s[i] = leaf[i];
  __syncthreads();
  for (int cnt = nleaves >> 1; cnt >= 1; cnt >>= 1) {
    float v[4];
    int nv = 0;
    for (int i = tid; i < cnt; i += 1024) { v[nv] = s[2 * i] + s[2 * i + 1]; ++nv; }
    __syncthreads();
    nv = 0;
    for (int i = tid; i < cnt; i += 1024) { s[i] = v[nv]; ++nv; }
    __syncthreads();
  }
  if (tid == 0) th[0] = s[0] * inv_n;
}

// ---------------- ternary quantize (fp32 compare vs numpy-exact th) ----------------
__global__ __launch_bounds__(256) void ternary_quant(const float* __restrict__ w,
                                                     const float* __restrict__ thp,
                                                     float* __restrict__ o, int n) {
  float th = thp[0];
  int i = blockIdx.x * 256 + threadIdx.x;
  if (i < n) {
    float x = w[i];
    o[i] = (x > th) ? 1.0f : ((x < -th) ? -1.0f : 0.0f);
  }
}

// ---------------- RMSNorm, one row/block, optional second gain ----------------
__global__ __launch_bounds__(256) void rmsnorm2(const float* __restrict__ X,
                                                const float* __restrict__ g1,
                                                const float* __restrict__ g2,
                                                float* __restrict__ O1,
                                                float* __restrict__ O2) {
  int row = blockIdx.x;
  const float* xr = X + (size_t)row * Dc;
  int tid = threadIdx.x;
  float4 v = *(const float4*)&xr[tid * 4];
  float ss = v.x * v.x + v.y * v.y + v.z * v.z + v.w * v.w;
#pragma unroll
  for (int off = 1; off < 64; off <<= 1) ss += __shfl_xor(ss, off);
  __shared__ float red[4];
  if ((tid & 63) == 0) red[tid >> 6] = ss;
  __syncthreads();
  float tot = red[0] + red[1] + red[2] + red[3];
  float inv = 1.0f / sqrtf(tot * (1.0f / (float)Dc) + EPSc);
  float4 a = *(const float4*)&g1[tid * 4];
  *(float4*)&O1[(size_t)row * Dc + tid * 4] =
      make_float4(v.x * inv * a.x, v.y * inv * a.y, v.z * inv * a.z, v.w * inv * a.w);
  if (O2 != nullptr) {
    float4 b2 = *(const float4*)&g2[tid * 4];
    *(float4*)&O2[(size_t)row * Dc + tid * 4] =
        make_float4(v.x * inv * b2.x, v.y * inv * b2.y, v.z * inv * b2.z, v.w * inv * b2.w);
  }
}

// ---------------- fp32 GEMM 128x64 tile, 8x4 acc, multi-mode epilogue ----------------
// mode 0: C fp32 [M][N]
// mode 1: O1/O2 = bf16 hi/lo of result, [M][N] u16
// mode 2: O1 = bf16 result transposed to Vt layout [(b*4 + n>>6)*64 + (n&63)][t]
__global__ __launch_bounds__(256) void gemm_nt_multi(const float* __restrict__ A,
                                                     const float* __restrict__ B,
                                                     int M, int N, int K, int mode,
                                                     float* __restrict__ C,
                                                     u16* __restrict__ O1,
                                                     u16* __restrict__ O2) {
  __shared__ float As[16][132];
  __shared__ float Bs[16][68];
  int tid = threadIdx.x;
  int bm = blockIdx.y * 128, bn = blockIdx.x * 64;
  int lr = tid >> 2;
  int lk = (tid & 3) * 4;
  int tm = tid & 15, tn = tid >> 4;
  float acc[8][4] = {};
  for (int kb = 0; kb < K; kb += 16) {
    float4 a0 = *(const float4*)&A[(size_t)(bm + lr) * K + kb + lk];
    float4 a1 = *(const float4*)&A[(size_t)(bm + 64 + lr) * K + kb + lk];
    float4 b0 = *(const float4*)&B[(size_t)(bn + lr) * K + kb + lk];
    As[lk + 0][lr] = a0.x; As[lk + 1][lr] = a0.y; As[lk + 2][lr] = a0.z; As[lk + 3][lr] = a0.w;
    As[lk + 0][64 + lr] = a1.x; As[lk + 1][64 + lr] = a1.y; As[lk + 2][64 + lr] = a1.z; As[lk + 3][64 + lr] = a1.w;
    Bs[lk + 0][lr] = b0.x; Bs[lk + 1][lr] = b0.y; Bs[lk + 2][lr] = b0.z; Bs[lk + 3][lr] = b0.w;
    __syncthreads();
#pragma unroll
    for (int k = 0; k < 16; ++k) {
      float4 aA = *(const float4*)&As[k][tm * 4];
      float4 aB = *(const float4*)&As[k][64 + tm * 4];
      float4 bb = *(const float4*)&Bs[k][tn * 4];
      float av[8] = {aA.x, aA.y, aA.z, aA.w, aB.x, aB.y, aB.z, aB.w};
#pragma unroll
      for (int i = 0; i < 8; ++i) {
        acc[i][0] += av[i] * bb.x;
        acc[i][1] += av[i] * bb.y;
        acc[i][2] += av[i] * bb.z;
        acc[i][3] += av[i] * bb.w;
      }
    }
    __syncthreads();
  }
  if (mode == 0) {
#pragma unroll
    for (int i = 0; i < 8; ++i) {
      int row = bm + ((i < 4) ? (tm * 4 + i) : (64 + tm * 4 + (i - 4)));
      *(float4*)&C[(size_t)row * N + bn + tn * 4] =
          make_float4(acc[i][0], acc[i][1], acc[i][2], acc[i][3]);
    }
  } else if (mode == 1) {
#pragma unroll
    for (int i = 0; i < 8; ++i) {
      int row = bm + ((i < 4) ? (tm * 4 + i) : (64 + tm * 4 + (i - 4)));
      u16x4 h4, l4;
#pragma unroll
      for (int j = 0; j < 4; ++j) {
        float v = acc[i][j];
        u16 hb = f2bf(v);
        float hv = bf2f(hb);
        h4[j] = hb;
        l4[j] = f2bf(v - hv);
      }
      *(u16x4*)&O1[(size_t)row * N + bn + tn * 4] = h4;
      *(u16x4*)&O2[(size_t)row * N + bn + tn * 4] = l4;
    }
  } else {
#pragma unroll
    for (int half = 0; half < 2; ++half) {
      int row0 = bm + half * 64 + tm * 4;
      int bb = row0 >> 11;
      int t0 = row0 & 2047;
#pragma unroll
      for (int j = 0; j < 4; ++j) {
        int n = bn + tn * 4 + j;
        size_t vrow = (size_t)(bb * 4 + (n >> 6)) * 64 + (n & 63);
        u16x4 o;
#pragma unroll
        for (int i = 0; i < 4; ++i) o[i] = f2bf(acc[half * 4 + i][j]);
        *(u16x4*)&O1[vrow * Tc + t0] = o;
      }
    }
  }
}

// ---------------- MFMA causal GQA attention ----------------
// bf16x3 QK^T (qh*kh + qh*kl + ql*kh), bf16 PV. Block = 64 q-rows, 4 waves x 16-row strip.
// Grid: (T/64, H, B), blockIdx.x reversed for load balance.
__global__ __launch_bounds__(256) void attn_mfma(const u16* __restrict__ Qh, const u16* __restrict__ Ql,
                                                 const u16* __restrict__ Kh, const u16* __restrict__ Kl,
                                                 const u16* __restrict__ Vt,
                                                 const float* __restrict__ qk_gain,
                                                 float* __restrict__ AO) {
  __shared__ __align__(16) u16 Qh_s[4096], Ql_s[4096];
  __shared__ __align__(16) u16 Kh_s[4096], Kl_s[4096], Vt_s[4096];
  __shared__ __align__(16) u16 Ps[4][1024];
  int tid = threadIdx.x;
  int w = tid >> 6, l = tid & 63;
  int qt = (int)gridDim.x - 1 - (int)blockIdx.x;
  int q0 = qt * 64;
  int h = blockIdx.y, b = blockIdx.z;
  int kvh = h >> 2;
  float sc = qk_gain[0] * 0.125f;
  // ---- stage Q tile (64 rows x 64 d), hi+lo, swizzled chunks ----
  {
    const size_t qbase = ((size_t)(b * Tc + q0)) * Dc + h * 64;
#pragma unroll
    for (int p = 0; p < 2; ++p) {
      int idx = tid + p * 256;
      int j = idx >> 3, c = idx & 7;
      u16x8 vh = *(const u16x8*)&Qh[qbase + (size_t)j * Dc + c * 8];
      u16x8 vl = *(const u16x8*)&Ql[qbase + (size_t)j * Dc + c * 8];
      int sw = (c * 8) ^ ((j & 7) << 3);
      *(u16x8*)&Qh_s[j * 64 + sw] = vh;
      *(u16x8*)&Ql_s[j * 64 + sw] = vl;
    }
  }
  __syncthreads();
  // ---- per-wave Q A-frags (row q = l&15 within strip, k-d = (l>>4)*8 + 32*sl) ----
  short8v qa_h[2], qa_l[2];
  {
    int q = w * 16 + (l & 15);
#pragma unroll
    for (int sl = 0; sl < 2; ++sl) {
      int dstart = ((l >> 4) * 8 + 32 * sl) ^ ((q & 7) << 3);
      qa_h[sl] = *(const short8v*)&Qh_s[q * 64 + dstart];
      qa_l[sl] = *(const short8v*)&Ql_s[q * 64 + dstart];
    }
  }
  f32x4 Oacc[4] = {{0,0,0,0},{0,0,0,0},{0,0,0,0},{0,0,0,0}};
  float mrow[4] = {-3.0e38f, -3.0e38f, -3.0e38f, -3.0e38f};
  float lrow[4] = {0.f, 0.f, 0.f, 0.f};
  int qmax_w = q0 + w * 16 + 15;
  int nsteps = qt + 1;
  u16* Ps_w = &Ps[w][0];
  for (int stp = 0; stp < nsteps; ++stp) {
    int k0 = stp * 64;
    __syncthreads();   // all waves done reading prev K/V tiles
    // ---- stage K hi/lo [64 keys][64 d] and V^T [64 d][64 t], swizzled ----
    {
#pragma unroll
      for (int p = 0; p < 2; ++p) {
        int idx = tid + p * 256;
        int jj = idx >> 3, cc = idx & 7;
        size_t kb = ((size_t)(b * Tc + k0 + jj)) * (HKVc * HDc) + kvh * 64 + cc * 8;
        u16x8 kh = *(const u16x8*)&Kh[kb];
        u16x8 kl = *(const u16x8*)&Kl[kb];
        int sw = (cc * 8) ^ ((jj & 7) << 3);
        *(u16x8*)&Kh_s[jj * 64 + sw] = kh;
        *(u16x8*)&Kl_s[jj * 64 + sw] = kl;
        size_t vb = ((size_t)((b * HKVc + kvh) * 64 + jj)) * Tc + k0 + cc * 8;
        u16x8 vv = *(const u16x8*)&Vt[vb];
        *(u16x8*)&Vt_s[jj * 64 + sw] = vv;
      }
    }
    __syncthreads();
    if (k0 > qmax_w) continue;   // fully-masked step for this wave (barriers already passed)
    // ---- QK^T: 4 key-subtiles x 2 k-slices x 3 mfma ----
    f32x4 s[4] = {{0,0,0,0},{0,0,0,0},{0,0,0,0},{0,0,0,0}};
#pragma unroll
    for (int kt = 0; kt < 4; ++kt) {
      int key = kt * 16 + (l & 15);
#pragma unroll
      for (int sl = 0; sl < 2; ++sl) {
        int dstart = ((l >> 4) * 8 + 32 * sl) ^ ((key & 7) << 3);
        short8v bh = *(const short8v*)&Kh_s[key * 64 + dstart];
        short8v bl = *(const short8v*)&Kl_s[key * 64 + dstart];
        s[kt] = __builtin_amdgcn_mfma_f32_16x16x32_bf16(qa_h[sl], bh, s[kt], 0, 0, 0);
        s[kt] = __builtin_amdgcn_mfma_f32_16x16x32_bf16(qa_h[sl], bl, s[kt], 0, 0, 0);
        s[kt] = __builtin_amdgcn_mfma_f32_16x16x32_bf16(qa_l[sl], bh, s[kt], 0, 0, 0);
      }
    }
    // ---- online softmax (D layout: col=key=l&15+16kt, row=q=(l>>4)*4+r) ----
#pragma unroll
    for (int r = 0; r < 4; ++r) {
      int qg = q0 + w * 16 + ((l >> 4) << 2) + r;
      int key0 = k0 + (l & 15);
      float t0 = s[0][r] * sc, t1 = s[1][r] * sc, t2 = s[2][r] * sc, t3 = s[3][r] * sc;
      t0 = (key0      <= qg) ? t0 : -3.0e38f;
      t1 = (key0 + 16 <= qg) ? t1 : -3.0e38f;
      t2 = (key0 + 32 <= qg) ? t2 : -3.0e38f;
      t3 = (key0 + 48 <= qg) ? t3 : -3.0e38f;
      float mx = fmaxf(fmaxf(t0, t1), fmaxf(t2, t3));
      mx = fmaxf(mx, __shfl_xor(mx, 1));
      mx = fmaxf(mx, __shfl_xor(mx, 2));
      mx = fmaxf(mx, __shfl_xor(mx, 4));
      mx = fmaxf(mx, __shfl_xor(mx, 8));
      float mnew = fmaxf(mrow[r], mx);
      float corr = __expf(mrow[r] - mnew);
      mrow[r] = mnew;
      float p0 = __expf(t0 - mnew), p1 = __expf(t1 - mnew);
      float p2 = __expf(t2 - mnew), p3 = __expf(t3 - mnew);
      float rs = (p0 + p1) + (p2 + p3);
      rs += __shfl_xor(rs, 1);
      rs += __shfl_xor(rs, 2);
      rs += __shfl_xor(rs, 4);
      rs += __shfl_xor(rs, 8);
      lrow[r] = lrow[r] * corr + rs;
      Oacc[0][r] *= corr; Oacc[1][r] *= corr; Oacc[2][r] *= corr; Oacc[3][r] *= corr;
      int qlocal = ((l >> 4) << 2) + r;
      int kb2 = (l & 15);
      int pbase = qlocal * 64;
      int px = (qlocal & 7) << 3;
      Ps_w[pbase + ((kb2)      ^ px)] = f2bf(p0);
      Ps_w[pbase + ((kb2 + 16) ^ px)] = f2bf(p1);
      Ps_w[pbase + ((kb2 + 32) ^ px)] = f2bf(p2);
      Ps_w[pbase + ((kb2 + 48) ^ px)] = f2bf(p3);
    }
    // ---- PV: A = P[16q x 32k] from Ps (within-wave; lgkmcnt ordering by compiler) ----
    short8v pa[2];
    {
      int qlocal = l & 15;
#pragma unroll
      for (int sl = 0; sl < 2; ++sl) {
        int kstart = ((l >> 4) * 8 + 32 * sl) ^ ((qlocal & 7) << 3);
        pa[sl] = *(const short8v*)&Ps_w[qlocal * 64 + kstart];
      }
    }
#pragma unroll
    for (int dt = 0; dt < 4; ++dt) {
      int d = dt * 16 + (l & 15);
#pragma unroll
      for (int sl = 0; sl < 2; ++sl) {
        int kstart = ((l >> 4) * 8 + 32 * sl) ^ ((d & 7) << 3);
        short8v vb = *(const short8v*)&Vt_s[d * 64 + kstart];
        Oacc[dt] = __builtin_amdgcn_mfma_f32_16x16x32_bf16(pa[sl], vb, Oacc[dt], 0, 0, 0);
      }
    }
  }
  // ---- epilogue: normalize and store (row q=(l>>4)*4+r, col d=l&15+16dt) ----
  size_t obase = ((size_t)(b * Tc + q0 + w * 16)) * Dc + h * 64;
#pragma unroll
  for (int r = 0; r < 4; ++r) {
    float invl = 1.0f / lrow[r];
    int q = ((l >> 4) << 2) + r;
#pragma unroll
    for (int dt = 0; dt < 4; ++dt) {
      AO[obase + (size_t)q * Dc + dt * 16 + (l & 15)] = Oacc[dt][r] * invl;
    }
  }
}

// ---------------- launch ----------------
extern "C" void kernel_launch(void* const* d_in, const int* in_sizes, int n_in,
                              void* d_out, int out_size, void* d_ws, size_t ws_size,
                              hipStream_t stream) {
  const float* x    = (const float*)d_in[0];
  const float* q_w  = (const float*)d_in[1];
  const float* q_g  = (const float*)d_in[2];
  const float* k_w  = (const float*)d_in[3];
  const float* k_g  = (const float*)d_in[4];
  const float* v_w  = (const float*)d_in[5];
  const float* o_w  = (const float*)d_in[6];
  const float* o_g  = (const float*)d_in[7];
  const float* qk_g = (const float*)d_in[8];

  // workspace layout; peak ~59.3 MB
  float* ws = (float*)d_ws;
  float* Wq   = ws;                          // 1M f (later overlaid by Wo)
  float* Wk   = Wq + 1048576;                // 256K f
  float* Xq   = Wk + 262144;                 // 4M f (later overlaid by AO)
  float* Xk   = Xq + 4194304;                // 4M f (later overlaid by Xo)
  u16*   Qh   = (u16*)(Xk + 4194304);        // 4M u16
  u16*   Ql   = Qh + 4194304;                // 4M u16
  u16*   Kh   = Ql + 4194304;                // 1M u16
  u16*   Kl   = Kh + 1048576;                // 1M u16
  u16*   Vt   = Kl + 1048576;                // 1M u16
  float* leaf = (float*)(Vt + 1048576);      // 8192 f
  float* th   = leaf + 8192;                 // 3 f
  float* AO   = Xq;                          // overlay: Xq dead after Q gemm
  float* Xo   = Xk;                          // overlay: Xk dead after K gemm
  float* Wo   = Wq;                          // overlay: Wq dead after Q gemm

  // 1) numpy-exact fp32 thresholds
  np_leafsum<<<256, 256, 0, stream>>>(q_w, leaf, 8192);
  np_treemean<<<1, 1024, 0, stream>>>(leaf, 8192, 1.0f / 1048576.0f, th + 0);
  np_leafsum<<<64, 256, 0, stream>>>(k_w, leaf, 2048);
  np_treemean<<<1, 1024, 0, stream>>>(leaf, 2048, 1.0f / 262144.0f, th + 1);
  np_leafsum<<<256, 256, 0, stream>>>(o_w, leaf, 8192);
  np_treemean<<<1, 1024, 0, stream>>>(leaf, 8192, 1.0f / 1048576.0f, th + 2);

  // 2) quantize q/k ternary weights
  ternary_quant<<<4096, 256, 0, stream>>>(q_w, th + 0, Wq, 1048576);
  ternary_quant<<<1024, 256, 0, stream>>>(k_w, th + 1, Wk, 262144);

  // 3) RMSNorm(x) with q_g and k_g gains
  rmsnorm2<<<Mc, 256, 0, stream>>>(x, q_g, k_g, Xq, Xk);

  // 4) projections: Q,K -> bf16 hi/lo; V -> bf16 transposed [b][kvh][d][t]
  gemm_nt_multi<<<dim3(16, 32), 256, 0, stream>>>(Xq, Wq, Mc, 1024, 1024, 1, nullptr, Qh, Ql);
  gemm_nt_multi<<<dim3(4, 32), 256, 0, stream>>>(Xk, Wk, Mc, 256, 1024, 1, nullptr, Kh, Kl);
  gemm_nt_multi<<<dim3(4, 32), 256, 0, stream>>>(x, v_w, Mc, 256, 1024, 2, nullptr, Vt, nullptr);

  // 5) MFMA causal GQA attention -> AO fp32 [4096,1024]
  attn_mfma<<<dim3(Tc / 64, Hc, Bc), 256, 0, stream>>>(Qh, Ql, Kh, Kl, Vt, qk_g, AO);

  // 6) output bitlinear: RMSNorm(AO)*o_g -> Xo; quantize o_w -> Wo; GEMM -> d_out
  rmsnorm2<<<Mc, 256, 0, stream>>>(AO, o_g, o_g, Xo, nullptr);
  ternary_quant<<<4096, 256, 0, stream>>>(o_w, th + 2, Wo, 1048576);
  gemm_nt_multi<<<dim3(16, 32), 256, 0, stream>>>(Xo, Wo, Mc, 1024, 1024, 0, (float*)d_out, nullptr, nullptr);
}

// Round 6
// 324.434 us; speedup vs baseline: 5.2002x; 1.8654x over previous
//
#include <hip/hip_runtime.h>
#include <hip/hip_bf16.h>
#include <cstdint>
#include <cstddef>

typedef unsigned short u16;
typedef unsigned int u32;
typedef __attribute__((ext_vector_type(8))) short short8v;   // 8 bf16 MFMA frag
typedef __attribute__((ext_vector_type(4))) float f32x4;     // MFMA accumulator
typedef __attribute__((ext_vector_type(4))) u16 u16x4;
typedef __attribute__((ext_vector_type(8))) u16 u16x8;

// Problem constants
static constexpr int Bc = 2, Tc = 2048, Dc = 1024, Hc = 16, HKVc = 4, HDc = 64;
static constexpr int Mc = Bc * Tc;                 // 4096 rows
static constexpr float EPSc = 1.1920929e-07f;

static __device__ __forceinline__ u16 f2bf(float f) {
  u32 u = __builtin_bit_cast(u32, f);
  return (u16)((u + 0x7fffu + ((u >> 16) & 1u)) >> 16);
}
static __device__ __forceinline__ float bf2f(u16 b) {
  u32 u = ((u32)b) << 16;
  return __builtin_bit_cast(float, u);
}

// ---------------- numpy-exact fp32 pairwise abs-mean (verified round 3) ----------------
__global__ __launch_bounds__(256) void np_leafsum(const float* __restrict__ w,
                                                  float* __restrict__ leaf, int nleaves) {
  int t = blockIdx.x * 256 + threadIdx.x;
  int lf = t >> 3, j = t & 7;
  if (lf >= nleaves) return;
  const float* a = w + (size_t)lf * 128;
  float r = fabsf(a[j]);
#pragma unroll
  for (int i = 8; i < 128; i += 8) r += fabsf(a[i + j]);
  float x = r + __shfl_xor(r, 1);
  float y = x + __shfl_xor(x, 2);
  float z = y + __shfl_xor(y, 4);
  if (j == 0) leaf[lf] = z;
}

__global__ __launch_bounds__(1024) void np_treemean(const float* __restrict__ leaf,
                                                    int nleaves, float inv_n,
                                                    float* __restrict__ th) {
  __shared__ float s[8192];
  int tid = threadIdx.x;
  for (int i = tid; i < nleaves; i += 1024) s[i] = leaf[i];
  __syncthreads();
  for (int cnt = nleaves >> 1; cnt >= 1; cnt >>= 1) {
    float v[4];
    int nv = 0;
    for (int i = tid; i < cnt; i += 1024) { v[nv] = s[2 * i] + s[2 * i + 1]; ++nv; }
    __syncthreads();
    nv = 0;
    for (int i = tid; i < cnt; i += 1024) { s[i] = v[nv]; ++nv; }
    __syncthreads();
  }
  if (tid == 0) th[0] = s[0] * inv_n;
}

// ---------------- ternary quantize -> bf16 {-1,0,+1} ----------------
__global__ __launch_bounds__(256) void ternary_quant_bf16(const float* __restrict__ w,
                                                          const float* __restrict__ thp,
                                                          u16* __restrict__ o, int n) {
  float th = thp[0];
  int i = blockIdx.x * 256 + threadIdx.x;
  if (i < n) {
    float x = w[i];
    o[i] = (x > th) ? (u16)0x3F80 : ((x < -th) ? (u16)0xBF80 : (u16)0);
  }
}

// ---------------- fp32 -> bf16 hi/lo split (elementwise, float4-vectorized) ----------------
__global__ __launch_bounds__(256) void split_hilo(const float* __restrict__ X,
                                                  u16* __restrict__ H, u16* __restrict__ L,
                                                  int n4) {
  int i = blockIdx.x * 256 + threadIdx.x;
  if (i >= n4) return;
  float4 v = *(const float4*)&X[(size_t)i * 4];
  float y[4] = {v.x, v.y, v.z, v.w};
  u16x4 h, l;
#pragma unroll
  for (int j = 0; j < 4; ++j) {
    u16 hb = f2bf(y[j]);
    h[j] = hb;
    l[j] = f2bf(y[j] - bf2f(hb));
  }
  *(u16x4*)&H[(size_t)i * 4] = h;
  *(u16x4*)&L[(size_t)i * 4] = l;
}

// ---------------- RMSNorm -> bf16 hi/lo, one row/block, optional second gain ----------------
__global__ __launch_bounds__(256) void rmsnorm_hilo(const float* __restrict__ X,
                                                    const float* __restrict__ g1,
                                                    const float* __restrict__ g2,
                                                    u16* __restrict__ H1, u16* __restrict__ L1,
                                                    u16* __restrict__ H2, u16* __restrict__ L2) {
  int row = blockIdx.x;
  const float* xr = X + (size_t)row * Dc;
  int tid = threadIdx.x;
  float4 v = *(const float4*)&xr[tid * 4];
  float ss = v.x * v.x + v.y * v.y + v.z * v.z + v.w * v.w;
#pragma unroll
  for (int off = 1; off < 64; off <<= 1) ss += __shfl_xor(ss, off);
  __shared__ float red[4];
  if ((tid & 63) == 0) red[tid >> 6] = ss;
  __syncthreads();
  float tot = red[0] + red[1] + red[2] + red[3];
  float inv = 1.0f / sqrtf(tot * (1.0f / (float)Dc) + EPSc);
  float vv[4] = {v.x, v.y, v.z, v.w};
  {
    float4 a = *(const float4*)&g1[tid * 4];
    float ga[4] = {a.x, a.y, a.z, a.w};
    u16x4 h, l;
#pragma unroll
    for (int j = 0; j < 4; ++j) {
      float y = vv[j] * inv * ga[j];
      u16 hb = f2bf(y);
      h[j] = hb;
      l[j] = f2bf(y - bf2f(hb));
    }
    *(u16x4*)&H1[(size_t)row * Dc + tid * 4] = h;
    *(u16x4*)&L1[(size_t)row * Dc + tid * 4] = l;
  }
  if (g2 != nullptr) {
    float4 a = *(const float4*)&g2[tid * 4];
    float ga[4] = {a.x, a.y, a.z, a.w};
    u16x4 h, l;
#pragma unroll
    for (int j = 0; j < 4; ++j) {
      float y = vv[j] * inv * ga[j];
      u16 hb = f2bf(y);
      h[j] = hb;
      l[j] = f2bf(y - bf2f(hb));
    }
    *(u16x4*)&H2[(size_t)row * Dc + tid * 4] = h;
    *(u16x4*)&L2[(size_t)row * Dc + tid * 4] = l;
  }
}

// ---------------- bf16 MFMA GEMM: C[M,N] = (Ah+Al)[M,K] @ (Bh(+Bl))[N,K]^T ----------------
// BM=BN=128, BK=64, 256 thr = 4 waves (2x2), wave tile 64x64, 4x4 16x16 frags.
// Register-prefetched staging, XOR-swizzled LDS (conflict-free, verified in attn).
// MODE 0: C fp32.  MODE 1: O1/O2 = bf16 hi/lo.  MODE 3: O1 = bf16.
#define LOADTILE(kb_)                                                          \
  {                                                                            \
    _Pragma("unroll") for (int p = 0; p < 4; ++p) {                            \
      int idx = tid + p * 256;                                                 \
      int row = idx >> 3, cc = idx & 7;                                        \
      rAh[p] = *(const u16x8*)&Ah[(size_t)(bm + row) * K + (kb_) + cc * 8];    \
      rAl[p] = *(const u16x8*)&Al[(size_t)(bm + row) * K + (kb_) + cc * 8];    \
      rBh[p] = *(const u16x8*)&Bh[(size_t)(bn + row) * K + (kb_) + cc * 8];    \
      if (PB) rBl[p] = *(const u16x8*)&Bl[(size_t)(bn + row) * K + (kb_) + cc * 8]; \
    }                                                                          \
  }

template <bool PB, int MODE>
__global__ __launch_bounds__(256, 1) void gemm_mfma(
    const u16* __restrict__ Ah, const u16* __restrict__ Al,
    const u16* __restrict__ Bh, const u16* __restrict__ Bl,
    int M, int N, int K,
    float* __restrict__ C, u16* __restrict__ O1, u16* __restrict__ O2) {
  __shared__ __align__(16) u16 AhS[8192], AlS[8192], BhS[8192], BlS[8192];
  int tid = threadIdx.x;
  int l = tid & 63, w = tid >> 6;
  int wm = (w >> 1) * 64, wn = (w & 1) * 64;
  int bm = blockIdx.y * 128, bn = blockIdx.x * 128;
  u16x8 rAh[4], rAl[4], rBh[4], rBl[4];
  f32x4 acc[4][4] = {};
  LOADTILE(0)
  for (int kb = 0; kb < K; kb += 64) {
    __syncthreads();
    // write prefetched tile to LDS (swizzled)
#pragma unroll
    for (int p = 0; p < 4; ++p) {
      int idx = tid + p * 256;
      int row = idx >> 3, cc = idx & 7;
      int off = row * 64 + ((cc * 8) ^ ((row & 7) << 3));
      *(u16x8*)&AhS[off] = rAh[p];
      *(u16x8*)&AlS[off] = rAl[p];
      *(u16x8*)&BhS[off] = rBh[p];
      if (PB) *(u16x8*)&BlS[off] = rBl[p];
    }
    if (kb + 64 < K) LOADTILE(kb + 64)
    __syncthreads();
    __builtin_amdgcn_s_setprio(1);
#pragma unroll
    for (int sl = 0; sl < 2; ++sl) {
      short8v fa[4], fal[4], fb[4], fbl[4];
      int kof = (l >> 4) * 8 + sl * 32;
#pragma unroll
      for (int m = 0; m < 4; ++m) {
        int row = wm + m * 16 + (l & 15);
        int off = row * 64 + (kof ^ ((row & 7) << 3));
        fa[m] = *(const short8v*)&AhS[off];
        fal[m] = *(const short8v*)&AlS[off];
      }
#pragma unroll
      for (int n = 0; n < 4; ++n) {
        int row = wn + n * 16 + (l & 15);
        int off = row * 64 + (kof ^ ((row & 7) << 3));
        fb[n] = *(const short8v*)&BhS[off];
        if (PB) fbl[n] = *(const short8v*)&BlS[off];
      }
#pragma unroll
      for (int m = 0; m < 4; ++m)
#pragma unroll
        for (int n = 0; n < 4; ++n) {
          acc[m][n] = __builtin_amdgcn_mfma_f32_16x16x32_bf16(fa[m], fb[n], acc[m][n], 0, 0, 0);
          acc[m][n] = __builtin_amdgcn_mfma_f32_16x16x32_bf16(fal[m], fb[n], acc[m][n], 0, 0, 0);
          if (PB)
            acc[m][n] = __builtin_amdgcn_mfma_f32_16x16x32_bf16(fa[m], fbl[n], acc[m][n], 0, 0, 0);
        }
    }
    __builtin_amdgcn_s_setprio(0);
  }
  // epilogue
#pragma unroll
  for (int m = 0; m < 4; ++m)
#pragma unroll
    for (int n = 0; n < 4; ++n)
#pragma unroll
      for (int r = 0; r < 4; ++r) {
        int grow = bm + wm + m * 16 + (l >> 4) * 4 + r;
        int gcol = bn + wn + n * 16 + (l & 15);
        float v = acc[m][n][r];
        if (MODE == 0) {
          C[(size_t)grow * N + gcol] = v;
        } else if (MODE == 1) {
          u16 hb = f2bf(v);
          O1[(size_t)grow * N + gcol] = hb;
          O2[(size_t)grow * N + gcol] = f2bf(v - bf2f(hb));
        } else {
          O1[(size_t)grow * N + gcol] = f2bf(v);
        }
      }
}

// ---------------- MFMA causal GQA attention (bf16x3 QK^T, bf16 PV) ----------------
// Block = 64 q-rows, 4 waves x 16-row strip. Q frags direct global->reg.
// K/V tiles register-prefetched into swizzled LDS. Grid: (T/64, H, B), x reversed.
__global__ __launch_bounds__(256, 4) void attn_mfma(
    const u16* __restrict__ Qh, const u16* __restrict__ Ql,
    const u16* __restrict__ Kh, const u16* __restrict__ Kl,
    const u16* __restrict__ Vt,
    const float* __restrict__ qk_gain,
    float* __restrict__ AO) {
  __shared__ __align__(16) u16 Kh_s[4096], Kl_s[4096], Vt_s[4096];
  __shared__ __align__(16) u16 Ps[4][1024];
  int tid = threadIdx.x;
  int w = tid >> 6, l = tid & 63;
  int qt = (int)gridDim.x - 1 - (int)blockIdx.x;
  int q0 = qt * 64;
  int h = blockIdx.y, b = blockIdx.z;
  int kvh = h >> 2;
  float sc = qk_gain[0] * 0.125f;
  // Q A-frags straight from global (row q = w*16 + (l&15))
  short8v qa_h[2], qa_l[2];
  {
    size_t qrow = (size_t)(b * Tc + q0 + w * 16 + (l & 15));
#pragma unroll
    for (int sl = 0; sl < 2; ++sl) {
      int dstart = (l >> 4) * 8 + sl * 32;
      qa_h[sl] = *(const short8v*)&Qh[qrow * Dc + h * 64 + dstart];
      qa_l[sl] = *(const short8v*)&Ql[qrow * Dc + h * 64 + dstart];
    }
  }
  f32x4 Oacc[4] = {{0,0,0,0},{0,0,0,0},{0,0,0,0},{0,0,0,0}};
  float mrow[4] = {-3.0e38f, -3.0e38f, -3.0e38f, -3.0e38f};
  float lrow[4] = {0.f, 0.f, 0.f, 0.f};
  int qmax_w = q0 + w * 16 + 15;
  int nsteps = qt + 1;
  u16* Ps_w = &Ps[w][0];
  u16x8 pkh[2], pkl[2], pvv[2];
#define AISSUE(K0)                                                              \
  {                                                                             \
    _Pragma("unroll") for (int p = 0; p < 2; ++p) {                             \
      int idx = tid + p * 256;                                                  \
      int jj = idx >> 3, cc = idx & 7;                                          \
      size_t kb = ((size_t)(b * Tc + (K0) + jj)) * (HKVc * HDc) + kvh * 64 + cc * 8; \
      pkh[p] = *(const u16x8*)&Kh[kb];                                          \
      pkl[p] = *(const u16x8*)&Kl[kb];                                          \
      size_t vb = ((size_t)(kvh * 64 + jj)) * (size_t)Mc + b * Tc + (K0) + cc * 8; \
      pvv[p] = *(const u16x8*)&Vt[vb];                                          \
    }                                                                           \
  }
  AISSUE(0)
  for (int stp = 0; stp < nsteps; ++stp) {
    int k0 = stp * 64;
    __syncthreads();   // all waves done reading prev K/V tiles
#pragma unroll
    for (int p = 0; p < 2; ++p) {
      int idx = tid + p * 256;
      int jj = idx >> 3, cc = idx & 7;
      int sw = jj * 64 + ((cc * 8) ^ ((jj & 7) << 3));
      *(u16x8*)&Kh_s[sw] = pkh[p];
      *(u16x8*)&Kl_s[sw] = pkl[p];
      *(u16x8*)&Vt_s[sw] = pvv[p];
    }
    if (stp + 1 < nsteps) AISSUE((stp + 1) * 64)
    __syncthreads();
    if (k0 > qmax_w) continue;   // fully-masked for this wave; no barriers skipped
    // ---- QK^T: 4 key-subtiles x 2 k-slices x 3 mfma ----
    f32x4 s[4] = {{0,0,0,0},{0,0,0,0},{0,0,0,0},{0,0,0,0}};
    __builtin_amdgcn_s_setprio(1);
#pragma unroll
    for (int kt = 0; kt < 4; ++kt) {
      int key = kt * 16 + (l & 15);
#pragma unroll
      for (int sl = 0; sl < 2; ++sl) {
        int dstart = ((l >> 4) * 8 + 32 * sl) ^ ((key & 7) << 3);
        short8v bh = *(const short8v*)&Kh_s[key * 64 + dstart];
        short8v bl = *(const short8v*)&Kl_s[key * 64 + dstart];
        s[kt] = __builtin_amdgcn_mfma_f32_16x16x32_bf16(qa_h[sl], bh, s[kt], 0, 0, 0);
        s[kt] = __builtin_amdgcn_mfma_f32_16x16x32_bf16(qa_h[sl], bl, s[kt], 0, 0, 0);
        s[kt] = __builtin_amdgcn_mfma_f32_16x16x32_bf16(qa_l[sl], bh, s[kt], 0, 0, 0);
      }
    }
    __builtin_amdgcn_s_setprio(0);
    // ---- online softmax ----
#pragma unroll
    for (int r = 0; r < 4; ++r) {
      int qg = q0 + w * 16 + ((l >> 4) << 2) + r;
      int key0 = k0 + (l & 15);
      float t0 = s[0][r] * sc, t1 = s[1][r] * sc, t2 = s[2][r] * sc, t3 = s[3][r] * sc;
      t0 = (key0      <= qg) ? t0 : -3.0e38f;
      t1 = (key0 + 16 <= qg) ? t1 : -3.0e38f;
      t2 = (key0 + 32 <= qg) ? t2 : -3.0e38f;
      t3 = (key0 + 48 <= qg) ? t3 : -3.0e38f;
      float mx = fmaxf(fmaxf(t0, t1), fmaxf(t2, t3));
      mx = fmaxf(mx, __shfl_xor(mx, 1));
      mx = fmaxf(mx, __shfl_xor(mx, 2));
      mx = fmaxf(mx, __shfl_xor(mx, 4));
      mx = fmaxf(mx, __shfl_xor(mx, 8));
      float mnew = fmaxf(mrow[r], mx);
      float corr = __expf(mrow[r] - mnew);
      mrow[r] = mnew;
      float p0 = __expf(t0 - mnew), p1 = __expf(t1 - mnew);
      float p2 = __expf(t2 - mnew), p3 = __expf(t3 - mnew);
      float rs = (p0 + p1) + (p2 + p3);
      rs += __shfl_xor(rs, 1);
      rs += __shfl_xor(rs, 2);
      rs += __shfl_xor(rs, 4);
      rs += __shfl_xor(rs, 8);
      lrow[r] = lrow[r] * corr + rs;
      Oacc[0][r] *= corr; Oacc[1][r] *= corr; Oacc[2][r] *= corr; Oacc[3][r] *= corr;
      int qlocal = ((l >> 4) << 2) + r;
      int kb2 = (l & 15);
      int pbase = qlocal * 64;
      int px = (qlocal & 7) << 3;
      Ps_w[pbase + ((kb2)      ^ px)] = f2bf(p0);
      Ps_w[pbase + ((kb2 + 16) ^ px)] = f2bf(p1);
      Ps_w[pbase + ((kb2 + 32) ^ px)] = f2bf(p2);
      Ps_w[pbase + ((kb2 + 48) ^ px)] = f2bf(p3);
    }
    // ---- PV ----
    short8v pa[2];
    {
      int qlocal = l & 15;
#pragma unroll
      for (int sl = 0; sl < 2; ++sl) {
        int kstart = ((l >> 4) * 8 + 32 * sl) ^ ((qlocal & 7) << 3);
        pa[sl] = *(const short8v*)&Ps_w[qlocal * 64 + kstart];
      }
    }
    __builtin_amdgcn_s_setprio(1);
#pragma unroll
    for (int dt = 0; dt < 4; ++dt) {
      int d = dt * 16 + (l & 15);
#pragma unroll
      for (int sl = 0; sl < 2; ++sl) {
        int kstart = ((l >> 4) * 8 + 32 * sl) ^ ((d & 7) << 3);
        short8v vb = *(const short8v*)&Vt_s[d * 64 + kstart];
        Oacc[dt] = __builtin_amdgcn_mfma_f32_16x16x32_bf16(pa[sl], vb, Oacc[dt], 0, 0, 0);
      }
    }
    __builtin_amdgcn_s_setprio(0);
  }
  // epilogue
  size_t obase = ((size_t)(b * Tc + q0 + w * 16)) * Dc + h * 64;
#pragma unroll
  for (int r = 0; r < 4; ++r) {
    float invl = 1.0f / lrow[r];
    int q = ((l >> 4) << 2) + r;
#pragma unroll
    for (int dt = 0; dt < 4; ++dt) {
      AO[obase + (size_t)q * Dc + dt * 16 + (l & 15)] = Oacc[dt][r] * invl;
    }
  }
}

// ---------------- launch ----------------
extern "C" void kernel_launch(void* const* d_in, const int* in_sizes, int n_in,
                              void* d_out, int out_size, void* d_ws, size_t ws_size,
                              hipStream_t stream) {
  const float* x    = (const float*)d_in[0];
  const float* q_w  = (const float*)d_in[1];
  const float* q_g  = (const float*)d_in[2];
  const float* k_w  = (const float*)d_in[3];
  const float* k_g  = (const float*)d_in[4];
  const float* v_w  = (const float*)d_in[5];
  const float* o_w  = (const float*)d_in[6];
  const float* o_g  = (const float*)d_in[7];
  const float* qk_g = (const float*)d_in[8];

  // workspace (bytes), peak ~61.1 MB
  char* base = (char*)d_ws;
  u16* Xqh = (u16*)(base + (0ull  << 20));   // 8MB
  u16* Xql = (u16*)(base + (8ull  << 20));   // 8MB
  u16* Xkh = (u16*)(base + (16ull << 20));   // 8MB
  u16* Xkl = (u16*)(base + (24ull << 20));   // 8MB
  u16* Xvh = (u16*)(base + (32ull << 20));   // 8MB
  u16* Xvl = (u16*)(base + (40ull << 20));   // 8MB
  u16* Kh  = (u16*)(base + (48ull << 20));   // 2MB
  u16* Kl  = (u16*)(base + (50ull << 20));   // 2MB
  u16* Vt  = (u16*)(base + (52ull << 20));   // 2MB  [256][4096]
  u16* Wq  = (u16*)(base + (54ull << 20));   // 2MB
  u16* Wk  = (u16*)(base + (56ull << 20));   // 0.5MB
  u16* Wo  = (u16*)(base + (57ull << 20));   // 2MB
  u16* Vwh = (u16*)(base + (59ull << 20));   // 0.5MB
  u16* Vwl = (u16*)(base + (60ull << 20));   // 0.5MB
  float* leaf = (float*)(base + (61ull << 20)); // 32KB
  float* th   = leaf + 8192;                 // 3
  // overlays
  float* AO  = (float*)base;                 // 16MB over Xqh/Xql (dead after Q-proj)
  u16* Xoh = Xkh; u16* Xol = Xkl;            // over Xk (dead after K-proj)
  u16* Qh  = Xvh; u16* Ql  = Xvl;            // over Xv (dead after V-proj)

  // 1) numpy-exact fp32 thresholds
  np_leafsum<<<256, 256, 0, stream>>>(q_w, leaf, 8192);
  np_treemean<<<1, 1024, 0, stream>>>(leaf, 8192, 1.0f / 1048576.0f, th + 0);
  np_leafsum<<<64, 256, 0, stream>>>(k_w, leaf, 2048);
  np_treemean<<<1, 1024, 0, stream>>>(leaf, 2048, 1.0f / 262144.0f, th + 1);
  np_leafsum<<<256, 256, 0, stream>>>(o_w, leaf, 8192);
  np_treemean<<<1, 1024, 0, stream>>>(leaf, 8192, 1.0f / 1048576.0f, th + 2);

  // 2) quantize ternary weights -> bf16 (exact)
  ternary_quant_bf16<<<4096, 256, 0, stream>>>(q_w, th + 0, Wq, 1048576);
  ternary_quant_bf16<<<1024, 256, 0, stream>>>(k_w, th + 1, Wk, 262144);
  ternary_quant_bf16<<<4096, 256, 0, stream>>>(o_w, th + 2, Wo, 1048576);

  // 3) hi/lo splits: v_w and raw x (for V path)
  split_hilo<<<256, 256, 0, stream>>>(v_w, Vwh, Vwl, 65536);
  split_hilo<<<4096, 256, 0, stream>>>(x, Xvh, Xvl, 1048576);

  // 4) RMSNorm(x) -> bf16 hi/lo with q_g and k_g gains
  rmsnorm_hilo<<<Mc, 256, 0, stream>>>(x, q_g, k_g, Xqh, Xql, Xkh, Xkl);

  // 5) projections (MFMA). V first (Q output overlays Xv).
  //    V: Vt[256][4096] = Vw @ x^T, 3-pass (ah*bh + al*bh + ah*bl)
  gemm_mfma<true, 3><<<dim3(32, 2), 256, 0, stream>>>(Vwh, Vwl, Xvh, Xvl, 256, Mc, 1024,
                                                      nullptr, Vt, nullptr);
  //    Q: hi/lo bf16 out (exact 2-pass: ternary weights have no lo part)
  gemm_mfma<false, 1><<<dim3(8, 32), 256, 0, stream>>>(Xqh, Xql, Wq, nullptr, Mc, 1024, 1024,
                                                       nullptr, Qh, Ql);
  //    K: hi/lo bf16 out
  gemm_mfma<false, 1><<<dim3(2, 32), 256, 0, stream>>>(Xkh, Xkl, Wk, nullptr, Mc, 256, 1024,
                                                       nullptr, Kh, Kl);

  // 6) MFMA causal GQA attention -> AO fp32
  attn_mfma<<<dim3(Tc / 64, Hc, Bc), 256, 0, stream>>>(Qh, Ql, Kh, Kl, Vt, qk_g, AO);

  // 7) output bitlinear: RMSNorm(AO)*o_g -> hi/lo; MFMA GEMM -> d_out fp32
  rmsnorm_hilo<<<Mc, 256, 0, stream>>>(AO, o_g, nullptr, Xoh, Xol, nullptr, nullptr);
  gemm_mfma<false, 0><<<dim3(8, 32), 256, 0, stream>>>(Xoh, Xol, Wo, nullptr, Mc, 1024, 1024,
                                                       (float*)d_out, nullptr, nullptr);
}

// Round 7
// 211.362 us; speedup vs baseline: 7.9821x; 1.5350x over previous
//
#include <hip/hip_runtime.h>
#include <hip/hip_bf16.h>
#include <cstdint>
#include <cstddef>

typedef unsigned short u16;
typedef unsigned int u32;
typedef __attribute__((ext_vector_type(8))) short short8v;   // 8 bf16 MFMA frag
typedef __attribute__((ext_vector_type(4))) float f32x4;     // MFMA accumulator
typedef __attribute__((ext_vector_type(4))) u16 u16x4;
typedef __attribute__((ext_vector_type(8))) u16 u16x8;

// Problem constants
static constexpr int Bc = 2, Tc = 2048, Dc = 1024, Hc = 16, HKVc = 4, HDc = 64;
static constexpr int Mc = Bc * Tc;                 // 4096 rows
static constexpr float EPSc = 1.1920929e-07f;

static __device__ __forceinline__ u16 f2bf(float f) {
  u32 u = __builtin_bit_cast(u32, f);
  return (u16)((u + 0x7fffu + ((u >> 16) & 1u)) >> 16);
}
static __device__ __forceinline__ float bf2f(u16 b) {
  u32 u = ((u32)b) << 16;
  return __builtin_bit_cast(float, u);
}

// ---------------- numpy-exact fp32 pairwise abs-mean, fused ----------------
// leaves of 128 elems, 8-acc pattern (verified bit-exact vs numpy in round 3).
// One launch covers q_w (blocks 0-255), k_w (256-319), o_w (320-575).
__global__ __launch_bounds__(256) void np_leafsum_all(const float* __restrict__ q_w,
                                                      const float* __restrict__ k_w,
                                                      const float* __restrict__ o_w,
                                                      float* __restrict__ leaf) {
  int blk = blockIdx.x;
  const float* w;
  float* out;
  int lfbase;
  if (blk < 256)      { w = q_w; out = leaf;         lfbase = blk * 32; }
  else if (blk < 320) { w = k_w; out = leaf + 8192;  lfbase = (blk - 256) * 32; }
  else                { w = o_w; out = leaf + 10240; lfbase = (blk - 320) * 32; }
  int t = threadIdx.x;
  int lf = lfbase + (t >> 3), j = t & 7;
  const float* a = w + (size_t)lf * 128;
  float r = fabsf(a[j]);
#pragma unroll
  for (int i = 8; i < 128; i += 8) r += fabsf(a[i + j]);
  float x = r + __shfl_xor(r, 1);
  float y = x + __shfl_xor(x, 2);
  float z = y + __shfl_xor(y, 4);
  if (j == 0) out[lf - lfbase + lfbase] = z;
}

// Binary-tree mean over leaves (exact np order; fp-add commutative so shfl_xor
// pairing reproduces left+right sums bit-exactly). 3 blocks, one per matrix.
__global__ __launch_bounds__(256) void np_treemean3(const float* __restrict__ leaf,
                                                    float* __restrict__ th) {
  int m = blockIdx.x;
  const float* src = leaf + (m == 0 ? 0 : (m == 1 ? 8192 : 10240));
  int nle = (m == 1) ? 2048 : 8192;
  float inv_n = (m == 1) ? (1.0f / 262144.0f) : (1.0f / 1048576.0f);
  int t = threadIdx.x;
  int chunk = nle >> 8;                      // 32 or 8, power of two
  float v[32];
  for (int i = 0; i < chunk; i += 4) {
    float4 f = *(const float4*)&src[t * chunk + i];
    v[i] = f.x; v[i + 1] = f.y; v[i + 2] = f.z; v[i + 3] = f.w;
  }
  for (int cnt = chunk >> 1; cnt >= 1; cnt >>= 1)
    for (int i = 0; i < cnt; ++i) v[i] = v[2 * i] + v[2 * i + 1];
  float s = v[0];
#pragma unroll
  for (int off = 1; off < 64; off <<= 1) s += __shfl_xor(s, off);
  __shared__ float red[4];
  if ((t & 63) == 0) red[t >> 6] = s;
  __syncthreads();
  if (t == 0) th[m] = ((red[0] + red[1]) + (red[2] + red[3])) * inv_n;
}

// ---------------- fused ternary quantize -> bf16 {-1,0,+1}, all 3 matrices ----------------
__global__ __launch_bounds__(256) void ternary_quant_all(const float* __restrict__ q_w,
                                                         const float* __restrict__ k_w,
                                                         const float* __restrict__ o_w,
                                                         const float* __restrict__ th,
                                                         u16* __restrict__ Wq,
                                                         u16* __restrict__ Wk,
                                                         u16* __restrict__ Wo) {
  int i4 = blockIdx.x * 256 + threadIdx.x;   // float4 index, 0..589823
  const float* w; u16* o; float t;
  int j;
  if (i4 < 262144)      { w = q_w; o = Wq; t = th[0]; j = i4; }
  else if (i4 < 327680) { w = k_w; o = Wk; t = th[1]; j = i4 - 262144; }
  else                  { w = o_w; o = Wo; t = th[2]; j = i4 - 327680; }
  float4 v = *(const float4*)&w[(size_t)j * 4];
  float y[4] = {v.x, v.y, v.z, v.w};
  u16x4 q;
#pragma unroll
  for (int c = 0; c < 4; ++c)
    q[c] = (y[c] > t) ? (u16)0x3F80 : ((y[c] < -t) ? (u16)0xBF80 : (u16)0);
  *(u16x4*)&o[(size_t)j * 4] = q;
}

// ---------------- RMSNorm -> bf16 hi/lo (2 gains) + raw-x hi/lo split ----------------
__global__ __launch_bounds__(256) void rmsnorm_split6(const float* __restrict__ X,
                                                      const float* __restrict__ g1,
                                                      const float* __restrict__ g2,
                                                      u16* __restrict__ H1, u16* __restrict__ L1,
                                                      u16* __restrict__ H2, u16* __restrict__ L2,
                                                      u16* __restrict__ HV, u16* __restrict__ LV) {
  int row = blockIdx.x;
  const float* xr = X + (size_t)row * Dc;
  int tid = threadIdx.x;
  float4 v = *(const float4*)&xr[tid * 4];
  float vv[4] = {v.x, v.y, v.z, v.w};
  if (HV != nullptr) {           // raw x split for the V path
    u16x4 h, l;
#pragma unroll
    for (int j = 0; j < 4; ++j) {
      u16 hb = f2bf(vv[j]);
      h[j] = hb;
      l[j] = f2bf(vv[j] - bf2f(hb));
    }
    *(u16x4*)&HV[(size_t)row * Dc + tid * 4] = h;
    *(u16x4*)&LV[(size_t)row * Dc + tid * 4] = l;
  }
  float ss = v.x * v.x + v.y * v.y + v.z * v.z + v.w * v.w;
#pragma unroll
  for (int off = 1; off < 64; off <<= 1) ss += __shfl_xor(ss, off);
  __shared__ float red[4];
  if ((tid & 63) == 0) red[tid >> 6] = ss;
  __syncthreads();
  float tot = red[0] + red[1] + red[2] + red[3];
  float inv = 1.0f / sqrtf(tot * (1.0f / (float)Dc) + EPSc);
  {
    float4 a = *(const float4*)&g1[tid * 4];
    float ga[4] = {a.x, a.y, a.z, a.w};
    u16x4 h, l;
#pragma unroll
    for (int j = 0; j < 4; ++j) {
      float y = vv[j] * inv * ga[j];
      u16 hb = f2bf(y);
      h[j] = hb;
      l[j] = f2bf(y - bf2f(hb));
    }
    *(u16x4*)&H1[(size_t)row * Dc + tid * 4] = h;
    *(u16x4*)&L1[(size_t)row * Dc + tid * 4] = l;
  }
  if (g2 != nullptr) {
    float4 a = *(const float4*)&g2[tid * 4];
    float ga[4] = {a.x, a.y, a.z, a.w};
    u16x4 h, l;
#pragma unroll
    for (int j = 0; j < 4; ++j) {
      float y = vv[j] * inv * ga[j];
      u16 hb = f2bf(y);
      h[j] = hb;
      l[j] = f2bf(y - bf2f(hb));
    }
    *(u16x4*)&H2[(size_t)row * Dc + tid * 4] = h;
    *(u16x4*)&L2[(size_t)row * Dc + tid * 4] = l;
  }
}

// ---------------- bf16 MFMA GEMM (unchanged from round 6, verified) ----------------
#define LOADTILE(kb_)                                                          \
  {                                                                            \
    _Pragma("unroll") for (int p = 0; p < 4; ++p) {                            \
      int idx = tid + p * 256;                                                 \
      int row = idx >> 3, cc = idx & 7;                                        \
      rAh[p] = *(const u16x8*)&Ah[(size_t)(bm + row) * K + (kb_) + cc * 8];    \
      rAl[p] = *(const u16x8*)&Al[(size_t)(bm + row) * K + (kb_) + cc * 8];    \
      rBh[p] = *(const u16x8*)&Bh[(size_t)(bn + row) * K + (kb_) + cc * 8];    \
      if (PB) rBl[p] = *(const u16x8*)&Bl[(size_t)(bn + row) * K + (kb_) + cc * 8]; \
    }                                                                          \
  }

template <bool PB, int MODE>
__global__ __launch_bounds__(256, 1) void gemm_mfma(
    const u16* __restrict__ Ah, const u16* __restrict__ Al,
    const u16* __restrict__ Bh, const u16* __restrict__ Bl,
    int M, int N, int K,
    float* __restrict__ C, u16* __restrict__ O1, u16* __restrict__ O2) {
  __shared__ __align__(16) u16 AhS[8192], AlS[8192], BhS[8192], BlS[8192];
  int tid = threadIdx.x;
  int l = tid & 63, w = tid >> 6;
  int wm = (w >> 1) * 64, wn = (w & 1) * 64;
  int bm = blockIdx.y * 128, bn = blockIdx.x * 128;
  u16x8 rAh[4], rAl[4], rBh[4], rBl[4];
  f32x4 acc[4][4] = {};
  LOADTILE(0)
  for (int kb = 0; kb < K; kb += 64) {
    __syncthreads();
#pragma unroll
    for (int p = 0; p < 4; ++p) {
      int idx = tid + p * 256;
      int row = idx >> 3, cc = idx & 7;
      int off = row * 64 + ((cc * 8) ^ ((row & 7) << 3));
      *(u16x8*)&AhS[off] = rAh[p];
      *(u16x8*)&AlS[off] = rAl[p];
      *(u16x8*)&BhS[off] = rBh[p];
      if (PB) *(u16x8*)&BlS[off] = rBl[p];
    }
    if (kb + 64 < K) LOADTILE(kb + 64)
    __syncthreads();
    __builtin_amdgcn_s_setprio(1);
#pragma unroll
    for (int sl = 0; sl < 2; ++sl) {
      short8v fa[4], fal[4], fb[4], fbl[4];
      int kof = (l >> 4) * 8 + sl * 32;
#pragma unroll
      for (int m = 0; m < 4; ++m) {
        int row = wm + m * 16 + (l & 15);
        int off = row * 64 + (kof ^ ((row & 7) << 3));
        fa[m] = *(const short8v*)&AhS[off];
        fal[m] = *(const short8v*)&AlS[off];
      }
#pragma unroll
      for (int n = 0; n < 4; ++n) {
        int row = wn + n * 16 + (l & 15);
        int off = row * 64 + (kof ^ ((row & 7) << 3));
        fb[n] = *(const short8v*)&BhS[off];
        if (PB) fbl[n] = *(const short8v*)&BlS[off];
      }
#pragma unroll
      for (int m = 0; m < 4; ++m)
#pragma unroll
        for (int n = 0; n < 4; ++n) {
          acc[m][n] = __builtin_amdgcn_mfma_f32_16x16x32_bf16(fa[m], fb[n], acc[m][n], 0, 0, 0);
          acc[m][n] = __builtin_amdgcn_mfma_f32_16x16x32_bf16(fal[m], fb[n], acc[m][n], 0, 0, 0);
          if (PB)
            acc[m][n] = __builtin_amdgcn_mfma_f32_16x16x32_bf16(fa[m], fbl[n], acc[m][n], 0, 0, 0);
        }
    }
    __builtin_amdgcn_s_setprio(0);
  }
#pragma unroll
  for (int m = 0; m < 4; ++m)
#pragma unroll
    for (int n = 0; n < 4; ++n)
#pragma unroll
      for (int r = 0; r < 4; ++r) {
        int grow = bm + wm + m * 16 + (l >> 4) * 4 + r;
        int gcol = bn + wn + n * 16 + (l & 15);
        float v = acc[m][n][r];
        if (MODE == 0) {
          C[(size_t)grow * N + gcol] = v;
        } else if (MODE == 1) {
          u16 hb = f2bf(v);
          O1[(size_t)grow * N + gcol] = hb;
          O2[(size_t)grow * N + gcol] = f2bf(v - bf2f(hb));
        } else {
          O1[(size_t)grow * N + gcol] = f2bf(v);
        }
      }
}

// ---------------- MFMA causal GQA attention v2 ----------------
// TK=128, pair-balanced grid: block processes q-tiles (31-pr) and pr -> 17 steps each.
// bf16x3 QK^T, bf16 PV, reg-prefetched swizzled LDS, 64KB -> 2 blocks/CU.
__global__ __launch_bounds__(256, 2) void attn_mfma2(
    const u16* __restrict__ Qh, const u16* __restrict__ Ql,
    const u16* __restrict__ Kh, const u16* __restrict__ Kl,
    const u16* __restrict__ Vt,
    const float* __restrict__ qk_gain,
    float* __restrict__ AO) {
  __shared__ __align__(16) u16 Kh_s[8192], Kl_s[8192], Vt_s[8192];  // [128k][64d], [64d][128k]
  __shared__ __align__(16) u16 Ps[4][2048];                         // per wave [16q][128k]
  int tid = threadIdx.x;
  int w = tid >> 6, l = tid & 63;
  int pr = blockIdx.x;                 // 0..15
  int h = blockIdx.y, b = blockIdx.z;
  int kvh = h >> 2;
  float sc = qk_gain[0] * 0.125f;
  u16* Ps_w = &Ps[w][0];
  u16x8 pk[4], pl[4], pv[4];
#define AISSUE2(K0)                                                             \
  {                                                                             \
    _Pragma("unroll") for (int p = 0; p < 4; ++p) {                             \
      int idx = tid + p * 256;                                                  \
      int jj = idx >> 3, cc = idx & 7;                                          \
      size_t kb = ((size_t)(b * Tc + (K0) + jj)) * (HKVc * HDc) + kvh * 64 + cc * 8; \
      pk[p] = *(const u16x8*)&Kh[kb];                                           \
      pl[p] = *(const u16x8*)&Kl[kb];                                           \
      int d = idx >> 4, c16 = idx & 15;                                         \
      size_t vb = ((size_t)(kvh * 64 + d)) * (size_t)Mc + b * Tc + (K0) + c16 * 8; \
      pv[p] = *(const u16x8*)&Vt[vb];                                           \
    }                                                                           \
  }
  for (int pass = 0; pass < 2; ++pass) {
    int qt = pass == 0 ? (31 - pr) : pr;
    int q0 = qt * 64;
    // Q A-frags straight from global
    short8v qa_h[2], qa_l[2];
    {
      size_t qrow = (size_t)(b * Tc + q0 + w * 16 + (l & 15));
#pragma unroll
      for (int sl = 0; sl < 2; ++sl) {
        int dstart = (l >> 4) * 8 + sl * 32;
        qa_h[sl] = *(const short8v*)&Qh[qrow * Dc + h * 64 + dstart];
        qa_l[sl] = *(const short8v*)&Ql[qrow * Dc + h * 64 + dstart];
      }
    }
    f32x4 Oacc[4] = {{0,0,0,0},{0,0,0,0},{0,0,0,0},{0,0,0,0}};
    float mrow[4] = {-3.0e38f, -3.0e38f, -3.0e38f, -3.0e38f};
    float lrow[4] = {0.f, 0.f, 0.f, 0.f};
    int qmax_w = q0 + w * 16 + 15;
    int nsteps = qt / 2 + 1;
    AISSUE2(0)
    for (int stp = 0; stp < nsteps; ++stp) {
      int k0 = stp * 128;
      __syncthreads();   // all waves done reading prev tiles
#pragma unroll
      for (int p = 0; p < 4; ++p) {
        int idx = tid + p * 256;
        int jj = idx >> 3, cc = idx & 7;
        *(u16x8*)&Kh_s[jj * 64 + ((cc * 8) ^ ((jj & 7) << 3))] = pk[p];
        *(u16x8*)&Kl_s[jj * 64 + ((cc * 8) ^ ((jj & 7) << 3))] = pl[p];
        int d = idx >> 4, c16 = idx & 15;
        *(u16x8*)&Vt_s[d * 128 + ((c16 * 8) ^ ((d & 7) << 3))] = pv[p];
      }
      if (stp + 1 < nsteps) AISSUE2((stp + 1) * 128)
      __syncthreads();
      if (k0 > qmax_w) continue;   // fully masked for this wave (barriers done)
      // ---- QK^T: 8 key-subtiles x 2 slices x 3 mfma ----
      f32x4 s[8] = {{0,0,0,0},{0,0,0,0},{0,0,0,0},{0,0,0,0},
                    {0,0,0,0},{0,0,0,0},{0,0,0,0},{0,0,0,0}};
      __builtin_amdgcn_s_setprio(1);
#pragma unroll
      for (int kt = 0; kt < 8; ++kt) {
        int key = kt * 16 + (l & 15);
#pragma unroll
        for (int sl = 0; sl < 2; ++sl) {
          int dstart = ((l >> 4) * 8 + 32 * sl) ^ ((key & 7) << 3);
          short8v bh = *(const short8v*)&Kh_s[key * 64 + dstart];
          short8v bl = *(const short8v*)&Kl_s[key * 64 + dstart];
          s[kt] = __builtin_amdgcn_mfma_f32_16x16x32_bf16(qa_h[sl], bh, s[kt], 0, 0, 0);
          s[kt] = __builtin_amdgcn_mfma_f32_16x16x32_bf16(qa_h[sl], bl, s[kt], 0, 0, 0);
          s[kt] = __builtin_amdgcn_mfma_f32_16x16x32_bf16(qa_l[sl], bh, s[kt], 0, 0, 0);
        }
      }
      __builtin_amdgcn_s_setprio(0);
      // ---- online softmax ----
#pragma unroll
      for (int r = 0; r < 4; ++r) {
        int qg = q0 + w * 16 + ((l >> 4) << 2) + r;
        int key0 = k0 + (l & 15);
        float t[8];
#pragma unroll
        for (int kt = 0; kt < 8; ++kt) {
          float v = s[kt][r] * sc;
          t[kt] = (key0 + kt * 16 <= qg) ? v : -3.0e38f;
        }
        float mx = fmaxf(fmaxf(fmaxf(t[0], t[1]), fmaxf(t[2], t[3])),
                         fmaxf(fmaxf(t[4], t[5]), fmaxf(t[6], t[7])));
        mx = fmaxf(mx, __shfl_xor(mx, 1));
        mx = fmaxf(mx, __shfl_xor(mx, 2));
        mx = fmaxf(mx, __shfl_xor(mx, 4));
        mx = fmaxf(mx, __shfl_xor(mx, 8));
        float mnew = fmaxf(mrow[r], mx);
        float corr = __expf(mrow[r] - mnew);
        mrow[r] = mnew;
        float p[8];
#pragma unroll
        for (int kt = 0; kt < 8; ++kt) p[kt] = __expf(t[kt] - mnew);
        float rs = ((p[0] + p[1]) + (p[2] + p[3])) + ((p[4] + p[5]) + (p[6] + p[7]));
        rs += __shfl_xor(rs, 1);
        rs += __shfl_xor(rs, 2);
        rs += __shfl_xor(rs, 4);
        rs += __shfl_xor(rs, 8);
        lrow[r] = lrow[r] * corr + rs;
        Oacc[0][r] *= corr; Oacc[1][r] *= corr; Oacc[2][r] *= corr; Oacc[3][r] *= corr;
        int qlocal = ((l >> 4) << 2) + r;
        int kb2 = (l & 15);
        int pbase = qlocal * 128;
        int px = (qlocal & 7) << 3;
#pragma unroll
        for (int kt = 0; kt < 8; ++kt)
          Ps_w[pbase + ((kb2 + 16 * kt) ^ px)] = f2bf(p[kt]);
      }
      // ---- PV: P[16q x 128k] @ V^T ----
      short8v pa[4];
      {
        int qlocal = l & 15;
#pragma unroll
        for (int sl = 0; sl < 4; ++sl) {
          int kstart = ((l >> 4) * 8 + 32 * sl) ^ ((qlocal & 7) << 3);
          pa[sl] = *(const short8v*)&Ps_w[qlocal * 128 + kstart];
        }
      }
      __builtin_amdgcn_s_setprio(1);
#pragma unroll
      for (int dt = 0; dt < 4; ++dt) {
        int d = dt * 16 + (l & 15);
#pragma unroll
        for (int sl = 0; sl < 4; ++sl) {
          int kstart = ((l >> 4) * 8 + 32 * sl) ^ ((d & 7) << 3);
          short8v vb = *(const short8v*)&Vt_s[d * 128 + kstart];
          Oacc[dt] = __builtin_amdgcn_mfma_f32_16x16x32_bf16(pa[sl], vb, Oacc[dt], 0, 0, 0);
        }
      }
      __builtin_amdgcn_s_setprio(0);
    }
    // epilogue
    size_t obase = ((size_t)(b * Tc + q0 + w * 16)) * Dc + h * 64;
#pragma unroll
    for (int r = 0; r < 4; ++r) {
      float invl = 1.0f / lrow[r];
      int q = ((l >> 4) << 2) + r;
#pragma unroll
      for (int dt = 0; dt < 4; ++dt) {
        AO[obase + (size_t)q * Dc + dt * 16 + (l & 15)] = Oacc[dt][r] * invl;
      }
    }
  }
}

// ---------------- launch ----------------
extern "C" void kernel_launch(void* const* d_in, const int* in_sizes, int n_in,
                              void* d_out, int out_size, void* d_ws, size_t ws_size,
                              hipStream_t stream) {
  const float* x    = (const float*)d_in[0];
  const float* q_w  = (const float*)d_in[1];
  const float* q_g  = (const float*)d_in[2];
  const float* k_w  = (const float*)d_in[3];
  const float* k_g  = (const float*)d_in[4];
  const float* v_w  = (const float*)d_in[5];
  const float* o_w  = (const float*)d_in[6];
  const float* o_g  = (const float*)d_in[7];
  const float* qk_g = (const float*)d_in[8];

  // workspace (bytes), peak ~61.2 MB
  char* base = (char*)d_ws;
  u16* Xqh = (u16*)(base + (0ull  << 20));   // 8MB
  u16* Xql = (u16*)(base + (8ull  << 20));   // 8MB
  u16* Xkh = (u16*)(base + (16ull << 20));   // 8MB
  u16* Xkl = (u16*)(base + (24ull << 20));   // 8MB
  u16* Xvh = (u16*)(base + (32ull << 20));   // 8MB
  u16* Xvl = (u16*)(base + (40ull << 20));   // 8MB
  u16* Kh  = (u16*)(base + (48ull << 20));   // 2MB
  u16* Kl  = (u16*)(base + (50ull << 20));   // 2MB
  u16* Vt  = (u16*)(base + (52ull << 20));   // 2MB  [256][4096]
  u16* Wq  = (u16*)(base + (54ull << 20));   // 2MB
  u16* Wk  = (u16*)(base + (56ull << 20));   // 0.5MB
  u16* Wo  = (u16*)(base + (57ull << 20));   // 2MB
  u16* Vwh = (u16*)(base + (59ull << 20));   // 0.5MB
  u16* Vwl = (u16*)(base + (60ull << 20));   // 0.5MB
  float* leaf = (float*)(base + (61ull << 20)); // 18432 floats (Q 8192 | K 2048 | O 8192)
  float* th   = leaf + 18432;                // 3
  // overlays
  float* AO  = (float*)base;                 // 16MB over Xqh/Xql (dead after Q-proj)
  u16* Xoh = Xkh; u16* Xol = Xkl;            // over Xk (dead after K-proj)
  u16* Qh  = Xvh; u16* Ql  = Xvl;            // over Xv (dead after V-proj)

  // 1) numpy-exact fp32 thresholds (fused: 1 leafsum launch + 1 treemean launch)
  np_leafsum_all<<<576, 256, 0, stream>>>(q_w, k_w, o_w, leaf);
  np_treemean3<<<3, 256, 0, stream>>>(leaf, th);

  // 2) quantize all ternary weights -> bf16 (one launch)
  ternary_quant_all<<<2304, 256, 0, stream>>>(q_w, k_w, o_w, th, Wq, Wk, Wo);

  // 3) v_w hi/lo split (small, via rmsnorm_split6 would be wrong shape; reuse quant grid? keep tiny kernel inline)
  //    fold into rmsnorm? v_w is [256][1024] - separate tiny launch via rmsnorm_split6 not possible.
  //    Use a 64-block split through rmsnorm_split6's raw-split path semantics:
  rmsnorm_split6<<<Mc, 256, 0, stream>>>(x, q_g, k_g, Xqh, Xql, Xkh, Xkl, Xvh, Xvl);
  {
    // v_w split: 256 rows of 1024 -> grid 256 blocks reusing split path only
    // (g1 output targets scratch region beyond live data? Instead: dedicated small kernel below)
  }
  // dedicated v_w hi/lo split (tiny)
  // NOTE: defined inline as a lambda-less global below
  extern __global__ void vw_split(const float*, u16*, u16*);
  vw_split<<<256, 256, 0, stream>>>(v_w, Vwh, Vwl);

  // 4) projections (MFMA). V first (Q output overlays Xv).
  gemm_mfma<true, 3><<<dim3(32, 2), 256, 0, stream>>>(Vwh, Vwl, Xvh, Xvl, 256, Mc, 1024,
                                                      nullptr, Vt, nullptr);
  gemm_mfma<false, 1><<<dim3(8, 32), 256, 0, stream>>>(Xqh, Xql, Wq, nullptr, Mc, 1024, 1024,
                                                       nullptr, Qh, Ql);
  gemm_mfma<false, 1><<<dim3(2, 32), 256, 0, stream>>>(Xkh, Xkl, Wk, nullptr, Mc, 256, 1024,
                                                       nullptr, Kh, Kl);

  // 5) MFMA causal GQA attention v2 -> AO fp32
  attn_mfma2<<<dim3(16, Hc, Bc), 256, 0, stream>>>(Qh, Ql, Kh, Kl, Vt, qk_g, AO);

  // 6) output bitlinear
  rmsnorm_split6<<<Mc, 256, 0, stream>>>(AO, o_g, nullptr, Xoh, Xol, nullptr, nullptr,
                                         nullptr, nullptr);
  gemm_mfma<false, 0><<<dim3(8, 32), 256, 0, stream>>>(Xoh, Xol, Wo, nullptr, Mc, 1024, 1024,
                                                       (float*)d_out, nullptr, nullptr);
}

// ---------------- v_w hi/lo split (tiny) ----------------
__global__ __launch_bounds__(256) void vw_split(const float* __restrict__ W,
                                                u16* __restrict__ H, u16* __restrict__ L) {
  int i = blockIdx.x * 256 + threadIdx.x;   // float4 index over 256*1024 = 262144 floats
  float4 v = *(const float4*)&W[(size_t)i * 4];
  float y[4] = {v.x, v.y, v.z, v.w};
  u16x4 h, l;
#pragma unroll
  for (int j = 0; j < 4; ++j) {
    u16 hb = f2bf(y[j]);
    h[j] = hb;
    l[j] = f2bf(y[j] - bf2f(hb));
  }
  *(u16x4*)&H[(size_t)i * 4] = h;
  *(u16x4*)&L[(size_t)i * 4] = l;
}

// Round 8
// 180.244 us; speedup vs baseline: 9.3602x; 1.1726x over previous
//
#include <hip/hip_runtime.h>
#include <hip/hip_bf16.h>
#include <cstdint>
#include <cstddef>

typedef unsigned short u16;
typedef unsigned int u32;
typedef __attribute__((ext_vector_type(8))) short short8v;   // 8 bf16 MFMA frag
typedef __attribute__((ext_vector_type(4))) float f32x4;     // MFMA accumulator
typedef __attribute__((ext_vector_type(4))) u16 u16x4;
typedef __attribute__((ext_vector_type(8))) u16 u16x8;

// Problem constants
static constexpr int Bc = 2, Tc = 2048, Dc = 1024, Hc = 16, HKVc = 4, HDc = 64;
static constexpr int Mc = Bc * Tc;                 // 4096 rows
static constexpr float EPSc = 1.1920929e-07f;

static __device__ __forceinline__ u16 f2bf(float f) {
  u32 u = __builtin_bit_cast(u32, f);
  return (u16)((u + 0x7fffu + ((u >> 16) & 1u)) >> 16);
}
static __device__ __forceinline__ float bf2f(u16 b) {
  u32 u = ((u32)b) << 16;
  return __builtin_bit_cast(float, u);
}
static __device__ __forceinline__ float fast_exp2(float x) {
  float r;
  asm("v_exp_f32 %0, %1" : "=v"(r) : "v"(x));
  return r;
}
static __device__ __forceinline__ u32 cvt_pk_bf16(float lo, float hi) {
  u32 r;
  asm("v_cvt_pk_bf16_f32 %0, %1, %2" : "=v"(r) : "v"(lo), "v"(hi));
  return r;
}

// ---------------- numpy-exact fp32 pairwise abs-mean (verified round 3/7) ----------------
__global__ __launch_bounds__(256) void np_leafsum_all(const float* __restrict__ q_w,
                                                      const float* __restrict__ k_w,
                                                      const float* __restrict__ o_w,
                                                      float* __restrict__ leaf) {
  int blk = blockIdx.x;
  const float* w;
  float* out;
  int lfbase;
  if (blk < 256)      { w = q_w; out = leaf;         lfbase = blk * 32; }
  else if (blk < 320) { w = k_w; out = leaf + 8192;  lfbase = (blk - 256) * 32; }
  else                { w = o_w; out = leaf + 10240; lfbase = (blk - 320) * 32; }
  int t = threadIdx.x;
  int lf = lfbase + (t >> 3), j = t & 7;
  const float* a = w + (size_t)lf * 128;
  float r = fabsf(a[j]);
#pragma unroll
  for (int i = 8; i < 128; i += 8) r += fabsf(a[i + j]);
  float x = r + __shfl_xor(r, 1);
  float y = x + __shfl_xor(x, 2);
  float z = y + __shfl_xor(y, 4);
  if (j == 0) out[lf] = z;
}

__global__ __launch_bounds__(256) void np_treemean3(const float* __restrict__ leaf,
                                                    float* __restrict__ th) {
  int m = blockIdx.x;
  const float* src = leaf + (m == 0 ? 0 : (m == 1 ? 8192 : 10240));
  int nle = (m == 1) ? 2048 : 8192;
  float inv_n = (m == 1) ? (1.0f / 262144.0f) : (1.0f / 1048576.0f);
  int t = threadIdx.x;
  int chunk = nle >> 8;                      // 32 or 8, power of two
  float v[32];
  for (int i = 0; i < chunk; i += 4) {
    float4 f = *(const float4*)&src[t * chunk + i];
    v[i] = f.x; v[i + 1] = f.y; v[i + 2] = f.z; v[i + 3] = f.w;
  }
  for (int cnt = chunk >> 1; cnt >= 1; cnt >>= 1)
    for (int i = 0; i < cnt; ++i) v[i] = v[2 * i] + v[2 * i + 1];
  float s = v[0];
#pragma unroll
  for (int off = 1; off < 64; off <<= 1) s += __shfl_xor(s, off);
  __shared__ float red[4];
  if ((t & 63) == 0) red[t >> 6] = s;
  __syncthreads();
  if (t == 0) th[m] = ((red[0] + red[1]) + (red[2] + red[3])) * inv_n;
}

// ---------------- fused: ternary quantize (q/k/o) + v_w hi/lo split ----------------
__global__ __launch_bounds__(256) void quant_split_all(const float* __restrict__ q_w,
                                                       const float* __restrict__ k_w,
                                                       const float* __restrict__ o_w,
                                                       const float* __restrict__ v_w,
                                                       const float* __restrict__ th,
                                                       u16* __restrict__ Wq,
                                                       u16* __restrict__ Wk,
                                                       u16* __restrict__ Wo,
                                                       u16* __restrict__ Vwh,
                                                       u16* __restrict__ Vwl) {
  int i4 = blockIdx.x * 256 + threadIdx.x;   // float4 index
  if (i4 < 589824) {
    const float* w; u16* o; float t;
    int j;
    if (i4 < 262144)      { w = q_w; o = Wq; t = th[0]; j = i4; }
    else if (i4 < 327680) { w = k_w; o = Wk; t = th[1]; j = i4 - 262144; }
    else                  { w = o_w; o = Wo; t = th[2]; j = i4 - 327680; }
    float4 v = *(const float4*)&w[(size_t)j * 4];
    float y[4] = {v.x, v.y, v.z, v.w};
    u16x4 q;
#pragma unroll
    for (int c = 0; c < 4; ++c)
      q[c] = (y[c] > t) ? (u16)0x3F80 : ((y[c] < -t) ? (u16)0xBF80 : (u16)0);
    *(u16x4*)&o[(size_t)j * 4] = q;
  } else {
    int j = i4 - 589824;                     // v_w float4 index, [0, 65536)
    float4 v = *(const float4*)&v_w[(size_t)j * 4];
    float y[4] = {v.x, v.y, v.z, v.w};
    u16x4 h, l;
#pragma unroll
    for (int c = 0; c < 4; ++c) {
      u16 hb = f2bf(y[c]);
      h[c] = hb;
      l[c] = f2bf(y[c] - bf2f(hb));
    }
    *(u16x4*)&Vwh[(size_t)j * 4] = h;
    *(u16x4*)&Vwl[(size_t)j * 4] = l;
  }
}

// ---------------- RMSNorm -> bf16 hi/lo (2 gains) + raw-x hi/lo split ----------------
__global__ __launch_bounds__(256) void rmsnorm_split6(const float* __restrict__ X,
                                                      const float* __restrict__ g1,
                                                      const float* __restrict__ g2,
                                                      u16* __restrict__ H1, u16* __restrict__ L1,
                                                      u16* __restrict__ H2, u16* __restrict__ L2,
                                                      u16* __restrict__ HV, u16* __restrict__ LV) {
  int row = blockIdx.x;
  const float* xr = X + (size_t)row * Dc;
  int tid = threadIdx.x;
  float4 v = *(const float4*)&xr[tid * 4];
  float vv[4] = {v.x, v.y, v.z, v.w};
  if (HV != nullptr) {           // raw x split for the V path
    u16x4 h, l;
#pragma unroll
    for (int j = 0; j < 4; ++j) {
      u16 hb = f2bf(vv[j]);
      h[j] = hb;
      l[j] = f2bf(vv[j] - bf2f(hb));
    }
    *(u16x4*)&HV[(size_t)row * Dc + tid * 4] = h;
    *(u16x4*)&LV[(size_t)row * Dc + tid * 4] = l;
  }
  float ss = v.x * v.x + v.y * v.y + v.z * v.z + v.w * v.w;
#pragma unroll
  for (int off = 1; off < 64; off <<= 1) ss += __shfl_xor(ss, off);
  __shared__ float red[4];
  if ((tid & 63) == 0) red[tid >> 6] = ss;
  __syncthreads();
  float tot = red[0] + red[1] + red[2] + red[3];
  float inv = 1.0f / sqrtf(tot * (1.0f / (float)Dc) + EPSc);
  {
    float4 a = *(const float4*)&g1[tid * 4];
    float ga[4] = {a.x, a.y, a.z, a.w};
    u16x4 h, l;
#pragma unroll
    for (int j = 0; j < 4; ++j) {
      float y = vv[j] * inv * ga[j];
      u16 hb = f2bf(y);
      h[j] = hb;
      l[j] = f2bf(y - bf2f(hb));
    }
    *(u16x4*)&H1[(size_t)row * Dc + tid * 4] = h;
    *(u16x4*)&L1[(size_t)row * Dc + tid * 4] = l;
  }
  if (g2 != nullptr) {
    float4 a = *(const float4*)&g2[tid * 4];
    float ga[4] = {a.x, a.y, a.z, a.w};
    u16x4 h, l;
#pragma unroll
    for (int j = 0; j < 4; ++j) {
      float y = vv[j] * inv * ga[j];
      u16 hb = f2bf(y);
      h[j] = hb;
      l[j] = f2bf(y - bf2f(hb));
    }
    *(u16x4*)&H2[(size_t)row * Dc + tid * 4] = h;
    *(u16x4*)&L2[(size_t)row * Dc + tid * 4] = l;
  }
}

// ---------------- bf16 MFMA GEMM, templated tile ----------------
// Block tile BM=MF*32 x BN=NF*32, BK=64, 256 thr = 4 waves (2x2), wave tile (BM/2)x(BN/2).
// MODE 0: C fp32.  MODE 1: O1/O2 = bf16 hi/lo.  MODE 3: O1 = bf16, key-permuted cols
// (col -> (col&~127) | ((col&15)<<3) | ((col>>4)&7)) to match attn's packed-P key order.
template <bool PB, int MODE, int MF, int NF>
__global__ __launch_bounds__(256, 1) void gemm_mfma(
    const u16* __restrict__ Ah, const u16* __restrict__ Al,
    const u16* __restrict__ Bh, const u16* __restrict__ Bl,
    int M, int N, int K,
    float* __restrict__ C, u16* __restrict__ O1, u16* __restrict__ O2) {
  constexpr int BM = MF * 32, BN = NF * 32;
  constexpr int APT = BM / 32;               // u16x8 loads per thread for A tile
  constexpr int BPT = BN / 32;
  __shared__ __align__(16) u16 AhS[BM * 64], AlS[BM * 64];
  __shared__ __align__(16) u16 BhS[BN * 64];
  __shared__ __align__(16) u16 BlS[PB ? BN * 64 : 8];
  int tid = threadIdx.x;
  int l = tid & 63, w = tid >> 6;
  int wm = (w >> 1) * (BM / 2), wn = (w & 1) * (BN / 2);
  int bm = blockIdx.y * BM, bn = blockIdx.x * BN;
  u16x8 rAh[APT], rAl[APT], rBh[BPT], rBl[PB ? BPT : 1];
  f32x4 acc[MF][NF] = {};
#define LOADTILE(kb_)                                                               \
  {                                                                                 \
    _Pragma("unroll") for (int p = 0; p < APT; ++p) {                               \
      int idx = tid + p * 256;                                                      \
      int row = idx >> 3, cc = idx & 7;                                             \
      rAh[p] = *(const u16x8*)&Ah[(size_t)(bm + row) * K + (kb_) + cc * 8];         \
      rAl[p] = *(const u16x8*)&Al[(size_t)(bm + row) * K + (kb_) + cc * 8];         \
    }                                                                               \
    _Pragma("unroll") for (int p = 0; p < BPT; ++p) {                               \
      int idx = tid + p * 256;                                                      \
      int row = idx >> 3, cc = idx & 7;                                             \
      rBh[p] = *(const u16x8*)&Bh[(size_t)(bn + row) * K + (kb_) + cc * 8];         \
      if (PB) rBl[p] = *(const u16x8*)&Bl[(size_t)(bn + row) * K + (kb_) + cc * 8]; \
    }                                                                               \
  }
  LOADTILE(0)
  for (int kb = 0; kb < K; kb += 64) {
    __syncthreads();
#pragma unroll
    for (int p = 0; p < APT; ++p) {
      int idx = tid + p * 256;
      int row = idx >> 3, cc = idx & 7;
      int off = row * 64 + ((cc * 8) ^ ((row & 7) << 3));
      *(u16x8*)&AhS[off] = rAh[p];
      *(u16x8*)&AlS[off] = rAl[p];
    }
#pragma unroll
    for (int p = 0; p < BPT; ++p) {
      int idx = tid + p * 256;
      int row = idx >> 3, cc = idx & 7;
      int off = row * 64 + ((cc * 8) ^ ((row & 7) << 3));
      *(u16x8*)&BhS[off] = rBh[p];
      if (PB) *(u16x8*)&BlS[off] = rBl[p];
    }
    if (kb + 64 < K) LOADTILE(kb + 64)
    __syncthreads();
    __builtin_amdgcn_s_setprio(1);
#pragma unroll
    for (int sl = 0; sl < 2; ++sl) {
      short8v fa[MF], fal[MF], fb[NF], fbl[NF];
      int kof = (l >> 4) * 8 + sl * 32;
#pragma unroll
      for (int m = 0; m < MF; ++m) {
        int row = wm + m * 16 + (l & 15);
        int off = row * 64 + (kof ^ ((row & 7) << 3));
        fa[m] = *(const short8v*)&AhS[off];
        fal[m] = *(const short8v*)&AlS[off];
      }
#pragma unroll
      for (int n = 0; n < NF; ++n) {
        int row = wn + n * 16 + (l & 15);
        int off = row * 64 + (kof ^ ((row & 7) << 3));
        fb[n] = *(const short8v*)&BhS[off];
        if (PB) fbl[n] = *(const short8v*)&BlS[off];
      }
#pragma unroll
      for (int m = 0; m < MF; ++m)
#pragma unroll
        for (int n = 0; n < NF; ++n) {
          acc[m][n] = __builtin_amdgcn_mfma_f32_16x16x32_bf16(fa[m], fb[n], acc[m][n], 0, 0, 0);
          acc[m][n] = __builtin_amdgcn_mfma_f32_16x16x32_bf16(fal[m], fb[n], acc[m][n], 0, 0, 0);
          if (PB)
            acc[m][n] = __builtin_amdgcn_mfma_f32_16x16x32_bf16(fa[m], fbl[n], acc[m][n], 0, 0, 0);
        }
    }
    __builtin_amdgcn_s_setprio(0);
  }
#undef LOADTILE
#pragma unroll
  for (int m = 0; m < MF; ++m)
#pragma unroll
    for (int n = 0; n < NF; ++n)
#pragma unroll
      for (int r = 0; r < 4; ++r) {
        int grow = bm + wm + m * 16 + (l >> 4) * 4 + r;
        int gcol = bn + wn + n * 16 + (l & 15);
        float v = acc[m][n][r];
        if (MODE == 0) {
          C[(size_t)grow * N + gcol] = v;
        } else if (MODE == 1) {
          u16 hb = f2bf(v);
          O1[(size_t)grow * N + gcol] = hb;
          O2[(size_t)grow * N + gcol] = f2bf(v - bf2f(hb));
        } else {
          int gp = (gcol & ~127) | (((gcol & 15) << 3) | ((gcol >> 4) & 7));
          O1[(size_t)grow * N + gp] = f2bf(v);
        }
      }
}

// ---------------- MFMA causal GQA attention v3 ----------------
// TK=128, pair-balanced grid (q-tiles 31-pr and pr). bf16x3 QK^T, bf16 PV.
// Packed-P: softmax emits one b128 per row via v_cvt_pk_bf16_f32; key axis permuted
// (slot c holds key (c&7)*16 + (c>>3)) consistently with V^T staging (V-GEMM epilogue).
__global__ __launch_bounds__(256, 2) void attn_mfma3(
    const u16* __restrict__ Qh, const u16* __restrict__ Ql,
    const u16* __restrict__ Kh, const u16* __restrict__ Kl,
    const u16* __restrict__ Vt,
    const float* __restrict__ qk_gain,
    float* __restrict__ AO) {
  __shared__ __align__(16) u16 Kh_s[8192], Kl_s[8192], Vt_s[8192];  // [128k][64d], [64d][128k']
  __shared__ __align__(16) u16 Ps[4][2048];                         // per wave [16q][128k']
  int tid = threadIdx.x;
  int w = tid >> 6, l = tid & 63;
  int pr = blockIdx.x;                 // 0..15
  int h = blockIdx.y, b = blockIdx.z;
  int kvh = h >> 2;
  const float sc2 = qk_gain[0] * 0.125f * 1.44269504f;   // fold log2(e): v_exp is 2^x
  u16* Ps_w = &Ps[w][0];
  u16x8 pk[4], pl[4], pv[4];
#define AISSUE2(K0)                                                             \
  {                                                                             \
    _Pragma("unroll") for (int p = 0; p < 4; ++p) {                             \
      int idx = tid + p * 256;                                                  \
      int jj = idx >> 3, cc = idx & 7;                                          \
      size_t kb = ((size_t)(b * Tc + (K0) + jj)) * (HKVc * HDc) + kvh * 64 + cc * 8; \
      pk[p] = *(const u16x8*)&Kh[kb];                                           \
      pl[p] = *(const u16x8*)&Kl[kb];                                           \
      int d = idx >> 4, c16 = idx & 15;                                         \
      size_t vb = ((size_t)(kvh * 64 + d)) * (size_t)Mc + b * Tc + (K0) + c16 * 8; \
      pv[p] = *(const u16x8*)&Vt[vb];                                           \
    }                                                                           \
  }
  for (int pass = 0; pass < 2; ++pass) {
    int qt = pass == 0 ? (31 - pr) : pr;
    int q0 = qt * 64;
    short8v qa_h[2], qa_l[2];
    {
      size_t qrow = (size_t)(b * Tc + q0 + w * 16 + (l & 15));
#pragma unroll
      for (int sl = 0; sl < 2; ++sl) {
        int dstart = (l >> 4) * 8 + sl * 32;
        qa_h[sl] = *(const short8v*)&Qh[qrow * Dc + h * 64 + dstart];
        qa_l[sl] = *(const short8v*)&Ql[qrow * Dc + h * 64 + dstart];
      }
    }
    f32x4 Oacc[4] = {{0,0,0,0},{0,0,0,0},{0,0,0,0},{0,0,0,0}};
    float mrow[4] = {-3.0e38f, -3.0e38f, -3.0e38f, -3.0e38f};
    float lrow[4] = {0.f, 0.f, 0.f, 0.f};
    int qmax_w = q0 + w * 16 + 15;
    int nsteps = qt / 2 + 1;
    AISSUE2(0)
    for (int stp = 0; stp < nsteps; ++stp) {
      int k0 = stp * 128;
      __syncthreads();
#pragma unroll
      for (int p = 0; p < 4; ++p) {
        int idx = tid + p * 256;
        int jj = idx >> 3, cc = idx & 7;
        *(u16x8*)&Kh_s[jj * 64 + ((cc * 8) ^ ((jj & 7) << 3))] = pk[p];
        *(u16x8*)&Kl_s[jj * 64 + ((cc * 8) ^ ((jj & 7) << 3))] = pl[p];
        int d = idx >> 4, c16 = idx & 15;
        *(u16x8*)&Vt_s[d * 128 + ((c16 * 8) ^ ((d & 7) << 3))] = pv[p];
      }
      if (stp + 1 < nsteps) AISSUE2((stp + 1) * 128)
      __syncthreads();
      if (k0 > qmax_w) continue;   // fully masked for this wave (barriers done)
      // ---- QK^T ----
      f32x4 s[8] = {{0,0,0,0},{0,0,0,0},{0,0,0,0},{0,0,0,0},
                    {0,0,0,0},{0,0,0,0},{0,0,0,0},{0,0,0,0}};
      __builtin_amdgcn_s_setprio(1);
#pragma unroll
      for (int kt = 0; kt < 8; ++kt) {
        int key = kt * 16 + (l & 15);
#pragma unroll
        for (int sl = 0; sl < 2; ++sl) {
          int dstart = ((l >> 4) * 8 + 32 * sl) ^ ((key & 7) << 3);
          short8v bh = *(const short8v*)&Kh_s[key * 64 + dstart];
          short8v bl = *(const short8v*)&Kl_s[key * 64 + dstart];
          s[kt] = __builtin_amdgcn_mfma_f32_16x16x32_bf16(qa_h[sl], bh, s[kt], 0, 0, 0);
          s[kt] = __builtin_amdgcn_mfma_f32_16x16x32_bf16(qa_h[sl], bl, s[kt], 0, 0, 0);
          s[kt] = __builtin_amdgcn_mfma_f32_16x16x32_bf16(qa_l[sl], bh, s[kt], 0, 0, 0);
        }
      }
      __builtin_amdgcn_s_setprio(0);
      // ---- online softmax (raw-unit max; scale folded into exp2 arg) ----
      bool full = (k0 + 127) <= (q0 + w * 16);   // wave-uniform: no masking needed
#pragma unroll
      for (int r = 0; r < 4; ++r) {
        float t[8];
        if (full) {
#pragma unroll
          for (int kt = 0; kt < 8; ++kt) t[kt] = s[kt][r];
        } else {
          int qg = q0 + w * 16 + ((l >> 4) << 2) + r;
          int key0 = k0 + (l & 15);
#pragma unroll
          for (int kt = 0; kt < 8; ++kt)
            t[kt] = (key0 + kt * 16 <= qg) ? s[kt][r] : -3.0e38f;
        }
        float mx = fmaxf(fmaxf(fmaxf(t[0], t[1]), fmaxf(t[2], t[3])),
                         fmaxf(fmaxf(t[4], t[5]), fmaxf(t[6], t[7])));
        mx = fmaxf(mx, __shfl_xor(mx, 1));
        mx = fmaxf(mx, __shfl_xor(mx, 2));
        mx = fmaxf(mx, __shfl_xor(mx, 4));
        mx = fmaxf(mx, __shfl_xor(mx, 8));
        float mnew = fmaxf(mrow[r], mx);
        float msc = mnew * sc2;
        float corr = fast_exp2(__builtin_fmaf(mrow[r], sc2, -msc));
        mrow[r] = mnew;
        float p[8];
#pragma unroll
        for (int kt = 0; kt < 8; ++kt)
          p[kt] = fast_exp2(__builtin_fmaf(t[kt], sc2, -msc));
        float rs = ((p[0] + p[1]) + (p[2] + p[3])) + ((p[4] + p[5]) + (p[6] + p[7]));
        rs += __shfl_xor(rs, 1);
        rs += __shfl_xor(rs, 2);
        rs += __shfl_xor(rs, 4);
        rs += __shfl_xor(rs, 8);
        lrow[r] = lrow[r] * corr + rs;
        Oacc[0][r] *= corr; Oacc[1][r] *= corr; Oacc[2][r] *= corr; Oacc[3][r] *= corr;
        // packed P store: slot c = kb2*8 + kt holds key kt*16 + kb2 (perm matches V)
        int qlocal = ((l >> 4) << 2) + r;
        int kb2 = (l & 15);
        uint4 pw;
        pw.x = cvt_pk_bf16(p[0], p[1]);
        pw.y = cvt_pk_bf16(p[2], p[3]);
        pw.z = cvt_pk_bf16(p[4], p[5]);
        pw.w = cvt_pk_bf16(p[6], p[7]);
        *(uint4*)&Ps_w[qlocal * 128 + ((kb2 * 8) ^ ((qlocal & 7) << 3))] = pw;
      }
      // ---- PV (permuted key order, consistent A/B) ----
      short8v pa[4];
      {
        int qlocal = l & 15;
#pragma unroll
        for (int sl = 0; sl < 4; ++sl) {
          int kstart = ((l >> 4) * 8 + 32 * sl) ^ ((qlocal & 7) << 3);
          pa[sl] = *(const short8v*)&Ps_w[qlocal * 128 + kstart];
        }
      }
      __builtin_amdgcn_s_setprio(1);
#pragma unroll
      for (int dt = 0; dt < 4; ++dt) {
        int d = dt * 16 + (l & 15);
#pragma unroll
        for (int sl = 0; sl < 4; ++sl) {
          int kstart = ((l >> 4) * 8 + 32 * sl) ^ ((d & 7) << 3);
          short8v vb = *(const short8v*)&Vt_s[d * 128 + kstart];
          Oacc[dt] = __builtin_amdgcn_mfma_f32_16x16x32_bf16(pa[sl], vb, Oacc[dt], 0, 0, 0);
        }
      }
      __builtin_amdgcn_s_setprio(0);
    }
    // epilogue
    size_t obase = ((size_t)(b * Tc + q0 + w * 16)) * Dc + h * 64;
#pragma unroll
    for (int r = 0; r < 4; ++r) {
      float invl = 1.0f / lrow[r];
      int q = ((l >> 4) << 2) + r;
#pragma unroll
      for (int dt = 0; dt < 4; ++dt) {
        AO[obase + (size_t)q * Dc + dt * 16 + (l & 15)] = Oacc[dt][r] * invl;
      }
    }
  }
}

// ---------------- launch ----------------
extern "C" void kernel_launch(void* const* d_in, const int* in_sizes, int n_in,
                              void* d_out, int out_size, void* d_ws, size_t ws_size,
                              hipStream_t stream) {
  const float* x    = (const float*)d_in[0];
  const float* q_w  = (const float*)d_in[1];
  const float* q_g  = (const float*)d_in[2];
  const float* k_w  = (const float*)d_in[3];
  const float* k_g  = (const float*)d_in[4];
  const float* v_w  = (const float*)d_in[5];
  const float* o_w  = (const float*)d_in[6];
  const float* o_g  = (const float*)d_in[7];
  const float* qk_g = (const float*)d_in[8];

  // workspace (bytes), peak ~61.2 MB
  char* base = (char*)d_ws;
  u16* Xqh = (u16*)(base + (0ull  << 20));   // 8MB
  u16* Xql = (u16*)(base + (8ull  << 20));   // 8MB
  u16* Xkh = (u16*)(base + (16ull << 20));   // 8MB
  u16* Xkl = (u16*)(base + (24ull << 20));   // 8MB
  u16* Xvh = (u16*)(base + (32ull << 20));   // 8MB
  u16* Xvl = (u16*)(base + (40ull << 20));   // 8MB
  u16* Kh  = (u16*)(base + (48ull << 20));   // 2MB
  u16* Kl  = (u16*)(base + (50ull << 20));   // 2MB
  u16* Vt  = (u16*)(base + (52ull << 20));   // 2MB  [256][4096], key-permuted per 128
  u16* Wq  = (u16*)(base + (54ull << 20));   // 2MB
  u16* Wk  = (u16*)(base + (56ull << 20));   // 0.5MB
  u16* Wo  = (u16*)(base + (57ull << 20));   // 2MB
  u16* Vwh = (u16*)(base + (59ull << 20));   // 0.5MB
  u16* Vwl = (u16*)(base + (60ull << 20));   // 0.5MB
  float* leaf = (float*)(base + (61ull << 20)); // 18432 floats (Q 8192 | K 2048 | O 8192)
  float* th   = leaf + 18432;                // 3
  // overlays
  float* AO  = (float*)base;                 // 16MB over Xqh/Xql (dead after Q-proj)
  u16* Xoh = Xkh; u16* Xol = Xkl;            // over Xk (dead after K-proj)
  u16* Qh  = Xvh; u16* Ql  = Xvl;            // over Xv (dead after V-proj)

  // 1) numpy-exact fp32 thresholds
  np_leafsum_all<<<576, 256, 0, stream>>>(q_w, k_w, o_w, leaf);
  np_treemean3<<<3, 256, 0, stream>>>(leaf, th);

  // 2) quantize ternary weights -> bf16 + v_w hi/lo split (one launch)
  quant_split_all<<<2560, 256, 0, stream>>>(q_w, k_w, o_w, v_w, th, Wq, Wk, Wo, Vwh, Vwl);

  // 3) RMSNorm(x) -> bf16 hi/lo (q,k gains) + raw-x hi/lo split (V path)
  rmsnorm_split6<<<Mc, 256, 0, stream>>>(x, q_g, k_g, Xqh, Xql, Xkh, Xkl, Xvh, Xvl);

  // 4) projections (MFMA). V first (Q output overlays Xv).
  //    V: Vt[256][4096] = Vw @ x^T (3-pass), key-permuted columns. 64x64 tiles, 256 blocks.
  gemm_mfma<true, 3, 2, 2><<<dim3(64, 4), 256, 0, stream>>>(Vwh, Vwl, Xvh, Xvl, 256, Mc, 1024,
                                                            nullptr, Vt, nullptr);
  //    Q: hi/lo bf16 out, 128x128 tiles.
  gemm_mfma<false, 1, 4, 4><<<dim3(8, 32), 256, 0, stream>>>(Xqh, Xql, Wq, nullptr, Mc, 1024, 1024,
                                                             nullptr, Qh, Ql);
  //    K: hi/lo bf16 out, 64x64 tiles, 256 blocks.
  gemm_mfma<false, 1, 2, 2><<<dim3(4, 64), 256, 0, stream>>>(Xkh, Xkl, Wk, nullptr, Mc, 256, 1024,
                                                             nullptr, Kh, Kl);

  // 5) MFMA causal GQA attention v3 -> AO fp32
  attn_mfma3<<<dim3(16, Hc, Bc), 256, 0, stream>>>(Qh, Ql, Kh, Kl, Vt, qk_g, AO);

  // 6) output bitlinear
  rmsnorm_split6<<<Mc, 256, 0, stream>>>(AO, o_g, nullptr, Xoh, Xol, nullptr, nullptr,
                                         nullptr, nullptr);
  gemm_mfma<false, 0, 4, 4><<<dim3(8, 32), 256, 0, stream>>>(Xoh, Xol, Wo, nullptr, Mc, 1024, 1024,
                                                             (float*)d_out, nullptr, nullptr);
}